// Round 2
// baseline (1411.236 us; speedup 1.0000x reference)
//
#include <hip/hip_runtime.h>

#define NN 100000
#define MM 20000
#define EE 1600000
// C = 128 channels, handled as 32 float4 per row.

static inline size_t align256(size_t x) { return (x + 255) & ~(size_t)255; }

// ---------------- zero fill (int region; 0 bits == 0.0f for the float part) --
__global__ void zero_i32_kernel(int* __restrict__ p, int n) {
  int i = blockIdx.x * blockDim.x + threadIdx.x;
  int stride = gridDim.x * blockDim.x;
  for (; i < n; i += stride) p[i] = 0;
}

// ---------------- histogram: per-edge count, per-node count, D -----------
__global__ __launch_bounds__(256) void count_kernel(
    const int* __restrict__ node_idx, const int* __restrict__ edge_idx,
    const float* __restrict__ hw,
    int* __restrict__ ecnt, int* __restrict__ ncnt, float* __restrict__ D) {
  int i = blockIdx.x * 256 + threadIdx.x;
  if (i >= EE) return;
  int n = node_idx[i];
  int e = edge_idx[i];
  atomicAdd(&ecnt[e], 1);
  atomicAdd(&ncnt[n], 1);
  atomicAdd(&D[n], hw[e]);
}

// ---------------- single-block exclusive scan: cnt[len] -> ptr[len+1] ----
__global__ __launch_bounds__(1024) void scan_kernel(
    const int* __restrict__ cnt, int len, int* __restrict__ ptr) {
  __shared__ int lds[1024];
  int t = threadIdx.x;
  int chunk = (len + 1023) >> 10;
  int lo = t * chunk;
  int hi = min(lo + chunk, len);
  int s = 0;
  for (int i = lo; i < hi; ++i) s += cnt[i];
  lds[t] = s;
  __syncthreads();
  for (int d = 1; d < 1024; d <<= 1) {
    int o = (t >= d) ? lds[t - d] : 0;
    __syncthreads();
    lds[t] += o;
    __syncthreads();
  }
  int excl = lds[t] - s;
  int run = excl;
  for (int i = lo; i < hi; ++i) { ptr[i] = run; run += cnt[i]; }
  if (t == 1023) ptr[len] = lds[1023];
}

// ---------------- 1/count and 1/D with 0-guard (matches _safe_inv) -------
__global__ void binv_kernel(const int* __restrict__ ecnt, float* __restrict__ Binv) {
  int m = blockIdx.x * 256 + threadIdx.x;
  if (m >= MM) return;
  int c = ecnt[m];
  Binv[m] = (c > 0) ? 1.0f / (float)c : 0.0f;
}
__global__ void dinv_kernel(const float* __restrict__ D, float* __restrict__ Dinv) {
  int n = blockIdx.x * 256 + threadIdx.x;
  if (n >= NN) return;
  float d = D[n];
  Dinv[n] = (d > 0.0f) ? 1.0f / d : 0.0f;
}

// ---------------- CSR fill (counting-sort placement) ---------------------
__global__ __launch_bounds__(256) void fill_kernel(
    const int* __restrict__ node_idx, const int* __restrict__ edge_idx,
    const int* __restrict__ eptr, const int* __restrict__ nptr,
    int* __restrict__ efill, int* __restrict__ nfill,
    int* __restrict__ edge_nodes, int* __restrict__ node_edges) {
  int i = blockIdx.x * 256 + threadIdx.x;
  if (i >= EE) return;
  int n = node_idx[i];
  int e = edge_idx[i];
  int p = atomicAdd(&efill[e], 1);
  edge_nodes[eptr[e] + p] = n;
  int q = atomicAdd(&nfill[n], 1);
  node_edges[nptr[n] + q] = e;
}

// ---------------- fp32 GEMM: Y[nrows,128] = X[nrows,128] @ W[128,128] ----
// W staged in LDS (64 KB). 256 thr/block, each thread: 4 rows x 8 cols.
__device__ __forceinline__ void fma4(float4& acc, float s, const float4& m) {
  acc.x += s * m.x;
  acc.y += s * m.y;
  acc.z += s * m.z;
  acc.w += s * m.w;
}

__global__ __launch_bounds__(256) void gemm128_kernel(
    const float* __restrict__ X, const float* __restrict__ W,
    float* __restrict__ Y, int nrows) {
  __shared__ float Wl[128 * 128];
  float4* Wl4 = (float4*)Wl;
  const float4* W4 = (const float4*)W;
  for (int i = threadIdx.x; i < 128 * 32; i += 256) Wl4[i] = W4[i];
  __syncthreads();

  int tc = threadIdx.x & 15;   // 16 column groups x 8 channels
  int tr = threadIdx.x >> 4;   // 16 row threads
  int base = blockIdx.x * 64;
  int r[4];
  bool v[4];
#pragma unroll
  for (int j = 0; j < 4; ++j) {
    int rr = base + tr + j * 16;
    v[j] = rr < nrows;
    r[j] = v[j] ? rr : 0;  // clamp loads, guard stores
  }
  const float4* X4 = (const float4*)X;
  float4 acc[4][2];
#pragma unroll
  for (int j = 0; j < 4; ++j) {
    acc[j][0] = make_float4(0.f, 0.f, 0.f, 0.f);
    acc[j][1] = make_float4(0.f, 0.f, 0.f, 0.f);
  }
#pragma unroll 4
  for (int k4 = 0; k4 < 32; ++k4) {
    float4 xv[4];
#pragma unroll
    for (int j = 0; j < 4; ++j) xv[j] = X4[(size_t)r[j] * 32 + k4];
#pragma unroll
    for (int kk = 0; kk < 4; ++kk) {
      float4 wva = Wl4[(k4 * 4 + kk) * 32 + tc * 2 + 0];
      float4 wvb = Wl4[(k4 * 4 + kk) * 32 + tc * 2 + 1];
#pragma unroll
      for (int j = 0; j < 4; ++j) {
        float xk = ((const float*)&xv[j])[kk];  // kk compile-time after unroll
        fma4(acc[j][0], xk, wva);
        fma4(acc[j][1], xk, wvb);
      }
    }
  }
  float4* Y4 = (float4*)Y;
#pragma unroll
  for (int j = 0; j < 4; ++j) {
    if (v[j]) {
      Y4[(size_t)r[j] * 32 + tc * 2 + 0] = acc[j][0];
      Y4[(size_t)r[j] * 32 + tc * 2 + 1] = acc[j][1];
    }
  }
}

// ---------------- edge aggregation: e[m] = Binv[m] * sum xt[members] -----
// half-wave (32 lanes x float4 = 128 ch) per edge; unroll-4 over members.
__global__ __launch_bounds__(256) void edge_agg_kernel(
    const float* __restrict__ xt, const int* __restrict__ eptr,
    const int* __restrict__ edge_nodes, const float* __restrict__ Binv,
    float* __restrict__ eout) {
  int half = threadIdx.x >> 5;
  int lane = threadIdx.x & 31;
  int m = blockIdx.x * 8 + half;
  if (m >= MM) return;
  int lo = eptr[m], hi = eptr[m + 1];
  const float4* xt4 = (const float4*)xt;
  float4 acc = make_float4(0.f, 0.f, 0.f, 0.f);
  int j = lo;
  for (; j + 4 <= hi; j += 4) {
    int n0 = edge_nodes[j + 0];
    int n1 = edge_nodes[j + 1];
    int n2 = edge_nodes[j + 2];
    int n3 = edge_nodes[j + 3];
    float4 a = xt4[(size_t)n0 * 32 + lane];
    float4 b = xt4[(size_t)n1 * 32 + lane];
    float4 c = xt4[(size_t)n2 * 32 + lane];
    float4 d = xt4[(size_t)n3 * 32 + lane];
    acc.x += (a.x + b.x) + (c.x + d.x);
    acc.y += (a.y + b.y) + (c.y + d.y);
    acc.z += (a.z + b.z) + (c.z + d.z);
    acc.w += (a.w + b.w) + (c.w + d.w);
  }
  for (; j < hi; ++j) {
    int n = edge_nodes[j];
    float4 a = xt4[(size_t)n * 32 + lane];
    acc.x += a.x; acc.y += a.y; acc.z += a.z; acc.w += a.w;
  }
  float bi = Binv[m];
  float4 rv;
  rv.x = acc.x * bi; rv.y = acc.y * bi; rv.z = acc.z * bi; rv.w = acc.w * bi;
  ((float4*)eout)[(size_t)m * 32 + lane] = rv;
}

// ---------------- node aggregation + bias + relu -------------------------
__global__ __launch_bounds__(256) void node_agg_kernel(
    const float* __restrict__ ein, const int* __restrict__ nptr,
    const int* __restrict__ node_edges, const float* __restrict__ Dinv,
    const float* __restrict__ bias, float* __restrict__ out) {
  int half = threadIdx.x >> 5;
  int lane = threadIdx.x & 31;
  int n = blockIdx.x * 8 + half;
  if (n >= NN) return;
  int lo = nptr[n], hi = nptr[n + 1];
  const float4* e4 = (const float4*)ein;
  float4 acc = make_float4(0.f, 0.f, 0.f, 0.f);
  int j = lo;
  for (; j + 4 <= hi; j += 4) {
    int m0 = node_edges[j + 0];
    int m1 = node_edges[j + 1];
    int m2 = node_edges[j + 2];
    int m3 = node_edges[j + 3];
    float4 a = e4[(size_t)m0 * 32 + lane];
    float4 b = e4[(size_t)m1 * 32 + lane];
    float4 c = e4[(size_t)m2 * 32 + lane];
    float4 d = e4[(size_t)m3 * 32 + lane];
    acc.x += (a.x + b.x) + (c.x + d.x);
    acc.y += (a.y + b.y) + (c.y + d.y);
    acc.z += (a.z + b.z) + (c.z + d.z);
    acc.w += (a.w + b.w) + (c.w + d.w);
  }
  for (; j < hi; ++j) {
    int m = node_edges[j];
    float4 a = e4[(size_t)m * 32 + lane];
    acc.x += a.x; acc.y += a.y; acc.z += a.z; acc.w += a.w;
  }
  float di = Dinv[n];
  float4 bb = ((const float4*)bias)[lane];
  float4 rv;
  rv.x = fmaxf(di * acc.x + bb.x, 0.f);
  rv.y = fmaxf(di * acc.y + bb.y, 0.f);
  rv.z = fmaxf(di * acc.z + bb.z, 0.f);
  rv.w = fmaxf(di * acc.w + bb.w, 0.f);
  ((float4*)out)[(size_t)n * 32 + lane] = rv;
}

// ---------------- host-side launch ---------------------------------------
extern "C" void kernel_launch(void* const* d_in, const int* in_sizes, int n_in,
                              void* d_out, int out_size, void* d_ws, size_t ws_size,
                              hipStream_t stream) {
  const float* x = (const float*)d_in[0];
  const int* hidx = (const int*)d_in[1];
  const int* node_idx = hidx;        // hyperedge_index[0]
  const int* edge_idx = hidx + EE;   // hyperedge_index[1]
  const float* hw = (const float*)d_in[2];
  // d_in[3] = hyperedge_attr (unused), d_in[4] = batch (unused)
  const float* W1 = (const float*)d_in[5];
  const float* b1 = (const float*)d_in[6];
  const float* W2 = (const float*)d_in[7];
  const float* b2 = (const float*)d_in[8];
  const float* W3 = (const float*)d_in[9];
  const float* b3 = (const float*)d_in[10];
  float* out = (float*)d_out;

  char* ws = (char*)d_ws;
  size_t off = 0;
  auto alloc = [&](size_t bytes) -> char* {
    char* p = ws + off;
    off = align256(off + bytes);
    return p;
  };
  float* xt   = (float*)alloc(sizeof(float) * (size_t)NN * 128);   // 51.2 MB
  float* h    = (float*)alloc(sizeof(float) * (size_t)NN * 128);   // 51.2 MB
  float* ebuf = (float*)alloc(sizeof(float) * (size_t)MM * 128);   // 10.24 MB
  // contiguous zero region: [ecnt MM][efill MM][ncnt NN][nfill NN][D NN]
  int*   zr    = (int*)alloc(sizeof(int) * (size_t)(2 * MM + 3 * NN));
  int*   ecnt  = zr;
  int*   efill = zr + MM;
  int*   ncnt  = zr + 2 * MM;
  int*   nfill = zr + 2 * MM + NN;
  float* D     = (float*)(zr + 2 * MM + 2 * NN);
  int*   eptr  = (int*)alloc(sizeof(int) * (MM + 1));
  int*   nptr  = (int*)alloc(sizeof(int) * (NN + 1));
  float* Binv  = (float*)alloc(sizeof(float) * MM);
  float* Dinv  = (float*)alloc(sizeof(float) * NN);
  int* edge_nodes = (int*)alloc(sizeof(int) * (size_t)EE);         // 6.4 MB
  int* node_edges = (int*)alloc(sizeof(int) * (size_t)EE);         // 6.4 MB
  (void)ws_size; (void)in_sizes; (void)n_in; (void)out_size;

  // ---- graph precompute (once per call; indices are runtime inputs) ----
  zero_i32_kernel<<<512, 256, 0, stream>>>(zr, 2 * MM + 3 * NN);
  count_kernel<<<EE / 256, 256, 0, stream>>>(node_idx, edge_idx, hw, ecnt, ncnt, D);
  scan_kernel<<<1, 1024, 0, stream>>>(ecnt, MM, eptr);
  scan_kernel<<<1, 1024, 0, stream>>>(ncnt, NN, nptr);
  binv_kernel<<<(MM + 255) / 256, 256, 0, stream>>>(ecnt, Binv);
  dinv_kernel<<<(NN + 255) / 256, 256, 0, stream>>>(D, Dinv);
  fill_kernel<<<EE / 256, 256, 0, stream>>>(node_idx, edge_idx, eptr, nptr,
                                            efill, nfill, edge_nodes, node_edges);

  const int gemm_grid = (NN + 63) / 64;
  const int eagg_grid = MM / 8;   // 20000 % 8 == 0
  const int nagg_grid = NN / 8;   // 100000 % 8 == 0

  // ---- layer 1 ----
  gemm128_kernel<<<gemm_grid, 256, 0, stream>>>(x, W1, xt, NN);
  edge_agg_kernel<<<eagg_grid, 256, 0, stream>>>(xt, eptr, edge_nodes, Binv, ebuf);
  node_agg_kernel<<<nagg_grid, 256, 0, stream>>>(ebuf, nptr, node_edges, Dinv, b1, h);
  // ---- layer 2 ----
  gemm128_kernel<<<gemm_grid, 256, 0, stream>>>(h, W2, xt, NN);
  edge_agg_kernel<<<eagg_grid, 256, 0, stream>>>(xt, eptr, edge_nodes, Binv, ebuf);
  node_agg_kernel<<<nagg_grid, 256, 0, stream>>>(ebuf, nptr, node_edges, Dinv, b2, h);
  // ---- layer 3 ----
  gemm128_kernel<<<gemm_grid, 256, 0, stream>>>(h, W3, xt, NN);
  edge_agg_kernel<<<eagg_grid, 256, 0, stream>>>(xt, eptr, edge_nodes, Binv, ebuf);
  node_agg_kernel<<<nagg_grid, 256, 0, stream>>>(ebuf, nptr, node_edges, Dinv, b3, out);
}

// Round 4
// 1336.914 us; speedup vs baseline: 1.0556x; 1.0556x over previous
//
#include <hip/hip_runtime.h>

#define NN 100000
#define MM 20000
#define EE 1600000
// C = 128 channels, handled as 32 float4 per row.

static inline size_t align256(size_t x) { return (x + 255) & ~(size_t)255; }

// ---------------- zero fill -----------------------------------------------
__global__ void zero_i32_kernel(int* __restrict__ p, int n) {
  int i = blockIdx.x * blockDim.x + threadIdx.x;
  int stride = gridDim.x * blockDim.x;
  for (; i < n; i += stride) p[i] = 0;
}

// ---------------- histogram: per-edge count + per-node count --------------
// 4 incidences per thread via int4 loads; 2 atomics per incidence.
__global__ __launch_bounds__(256) void count_kernel(
    const int* __restrict__ node_idx, const int* __restrict__ edge_idx,
    int* __restrict__ ecnt, int* __restrict__ ncnt) {
  int i = blockIdx.x * 256 + threadIdx.x;   // quad index
  if (i >= EE / 4) return;
  int4 nv = ((const int4*)node_idx)[i];
  int4 ev = ((const int4*)edge_idx)[i];
  atomicAdd(&ecnt[ev.x], 1);
  atomicAdd(&ecnt[ev.y], 1);
  atomicAdd(&ecnt[ev.z], 1);
  atomicAdd(&ecnt[ev.w], 1);
  atomicAdd(&ncnt[nv.x], 1);
  atomicAdd(&ncnt[nv.y], 1);
  atomicAdd(&ncnt[nv.z], 1);
  atomicAdd(&ncnt[nv.w], 1);
}

// ---------------- single-block exclusive scan: cnt[len] -> ptr[len+1] ----
// Optionally writes inv[i] = cnt[i]>0 ? 1/cnt[i] : 0 (B^{-1}).
__global__ __launch_bounds__(1024) void scan_kernel(
    const int* __restrict__ cnt, int len, int* __restrict__ ptr,
    float* __restrict__ inv) {
  __shared__ int lds[1024];
  int t = threadIdx.x;
  int chunk = (len + 1023) >> 10;
  int lo = t * chunk;
  int hi = min(lo + chunk, len);
  int s = 0;
  for (int i = lo; i < hi; ++i) s += cnt[i];
  lds[t] = s;
  __syncthreads();
  for (int d = 1; d < 1024; d <<= 1) {
    int o = (t >= d) ? lds[t - d] : 0;
    __syncthreads();
    lds[t] += o;
    __syncthreads();
  }
  int excl = lds[t] - s;
  int run = excl;
  for (int i = lo; i < hi; ++i) {
    ptr[i] = run;
    int c = cnt[i];
    run += c;
    if (inv) inv[i] = (c > 0) ? 1.0f / (float)c : 0.0f;
  }
  if (t == 1023) ptr[len] = lds[1023];
}

// ---------------- CSR fill (counting-sort placement), 4/thread ------------
__global__ __launch_bounds__(256) void fill_kernel(
    const int* __restrict__ node_idx, const int* __restrict__ edge_idx,
    const int* __restrict__ eptr, const int* __restrict__ nptr,
    int* __restrict__ efill, int* __restrict__ nfill,
    int* __restrict__ edge_nodes, int* __restrict__ node_edges) {
  int i = blockIdx.x * 256 + threadIdx.x;   // quad index
  if (i >= EE / 4) return;
  int4 nv = ((const int4*)node_idx)[i];
  int4 ev = ((const int4*)edge_idx)[i];
  int n[4] = {nv.x, nv.y, nv.z, nv.w};
  int e[4] = {ev.x, ev.y, ev.z, ev.w};
#pragma unroll
  for (int j = 0; j < 4; ++j) {
    int p = atomicAdd(&efill[e[j]], 1);
    edge_nodes[eptr[e[j]] + p] = n[j];
    int q = atomicAdd(&nfill[n[j]], 1);
    node_edges[nptr[n[j]] + q] = e[j];
  }
}

// ---------------- Dinv from node CSR (no atomics) -------------------------
// D[n] = sum over incident edges of hw[e]; Dinv = safe_inv(D).
__global__ __launch_bounds__(256) void dinv_csr_kernel(
    const int* __restrict__ nptr, const int* __restrict__ node_edges,
    const float* __restrict__ hw, float* __restrict__ Dinv) {
  int n = blockIdx.x * 256 + threadIdx.x;
  if (n >= NN) return;
  int lo = nptr[n], hi = nptr[n + 1];
  float d = 0.0f;
  for (int j = lo; j < hi; ++j) d += hw[node_edges[j]];
  Dinv[n] = (d > 0.0f) ? 1.0f / d : 0.0f;
}

// ---------------- fp32 GEMM: Y[nrows,128] = X[nrows,128] @ W[128,128] ----
// W staged in LDS (64 KB). 256 thr/block, each thread: 4 rows x 8 cols.
// Column partition per thread: float4 groups {tc} and {16+tc} -> 16-lane
// LDS reads are 256B contiguous (2-way bank aliasing only, free).
__device__ __forceinline__ void fma4(float4& acc, float s, const float4& m) {
  acc.x += s * m.x;
  acc.y += s * m.y;
  acc.z += s * m.z;
  acc.w += s * m.w;
}

__global__ __launch_bounds__(256) void gemm128_kernel(
    const float* __restrict__ X, const float* __restrict__ W,
    float* __restrict__ Y, int nrows) {
  __shared__ float Wl[128 * 128];
  float4* Wl4 = (float4*)Wl;
  const float4* W4 = (const float4*)W;
  for (int i = threadIdx.x; i < 128 * 32; i += 256) Wl4[i] = W4[i];
  __syncthreads();

  int tc = threadIdx.x & 15;   // 16 column threads
  int tr = threadIdx.x >> 4;   // 16 row threads
  int base = blockIdx.x * 64;
  int r[4];
  bool v[4];
#pragma unroll
  for (int j = 0; j < 4; ++j) {
    int rr = base + tr + j * 16;
    v[j] = rr < nrows;
    r[j] = v[j] ? rr : 0;  // clamp loads, guard stores
  }
  const float4* X4 = (const float4*)X;
  float4 acc[4][2];
#pragma unroll
  for (int j = 0; j < 4; ++j) {
    acc[j][0] = make_float4(0.f, 0.f, 0.f, 0.f);
    acc[j][1] = make_float4(0.f, 0.f, 0.f, 0.f);
  }
#pragma unroll 4
  for (int k4 = 0; k4 < 32; ++k4) {
    float4 xv[4];
#pragma unroll
    for (int j = 0; j < 4; ++j) xv[j] = X4[(size_t)r[j] * 32 + k4];
#pragma unroll
    for (int kk = 0; kk < 4; ++kk) {
      float4 wva = Wl4[(k4 * 4 + kk) * 32 + tc];
      float4 wvb = Wl4[(k4 * 4 + kk) * 32 + 16 + tc];
#pragma unroll
      for (int j = 0; j < 4; ++j) {
        float xk = ((const float*)&xv[j])[kk];  // kk compile-time after unroll
        fma4(acc[j][0], xk, wva);
        fma4(acc[j][1], xk, wvb);
      }
    }
  }
  float4* Y4 = (float4*)Y;
#pragma unroll
  for (int j = 0; j < 4; ++j) {
    if (v[j]) {
      Y4[(size_t)r[j] * 32 + tc] = acc[j][0];
      Y4[(size_t)r[j] * 32 + 16 + tc] = acc[j][1];
    }
  }
}

// ---------------- edge aggregation: e[m] = Binv[m] * sum xt[members] -----
// half-wave (32 lanes x float4 = 128 ch) per edge; unroll-4 over members.
__global__ __launch_bounds__(256) void edge_agg_kernel(
    const float* __restrict__ xt, const int* __restrict__ eptr,
    const int* __restrict__ edge_nodes, const float* __restrict__ Binv,
    float* __restrict__ eout) {
  int half = threadIdx.x >> 5;
  int lane = threadIdx.x & 31;
  int m = blockIdx.x * 8 + half;
  if (m >= MM) return;
  int lo = eptr[m], hi = eptr[m + 1];
  const float4* xt4 = (const float4*)xt;
  float4 acc = make_float4(0.f, 0.f, 0.f, 0.f);
  int j = lo;
  for (; j + 4 <= hi; j += 4) {
    int n0 = edge_nodes[j + 0];
    int n1 = edge_nodes[j + 1];
    int n2 = edge_nodes[j + 2];
    int n3 = edge_nodes[j + 3];
    float4 a = xt4[(size_t)n0 * 32 + lane];
    float4 b = xt4[(size_t)n1 * 32 + lane];
    float4 c = xt4[(size_t)n2 * 32 + lane];
    float4 d = xt4[(size_t)n3 * 32 + lane];
    acc.x += (a.x + b.x) + (c.x + d.x);
    acc.y += (a.y + b.y) + (c.y + d.y);
    acc.z += (a.z + b.z) + (c.z + d.z);
    acc.w += (a.w + b.w) + (c.w + d.w);
  }
  for (; j < hi; ++j) {
    int n = edge_nodes[j];
    float4 a = xt4[(size_t)n * 32 + lane];
    acc.x += a.x; acc.y += a.y; acc.z += a.z; acc.w += a.w;
  }
  float bi = Binv[m];
  float4 rv;
  rv.x = acc.x * bi; rv.y = acc.y * bi; rv.z = acc.z * bi; rv.w = acc.w * bi;
  ((float4*)eout)[(size_t)m * 32 + lane] = rv;
}

// ---------------- node aggregation + bias + relu -------------------------
__global__ __launch_bounds__(256) void node_agg_kernel(
    const float* __restrict__ ein, const int* __restrict__ nptr,
    const int* __restrict__ node_edges, const float* __restrict__ Dinv,
    const float* __restrict__ bias, float* __restrict__ out) {
  int half = threadIdx.x >> 5;
  int lane = threadIdx.x & 31;
  int n = blockIdx.x * 8 + half;
  if (n >= NN) return;
  int lo = nptr[n], hi = nptr[n + 1];
  const float4* e4 = (const float4*)ein;
  float4 acc = make_float4(0.f, 0.f, 0.f, 0.f);
  int j = lo;
  for (; j + 4 <= hi; j += 4) {
    int m0 = node_edges[j + 0];
    int m1 = node_edges[j + 1];
    int m2 = node_edges[j + 2];
    int m3 = node_edges[j + 3];
    float4 a = e4[(size_t)m0 * 32 + lane];
    float4 b = e4[(size_t)m1 * 32 + lane];
    float4 c = e4[(size_t)m2 * 32 + lane];
    float4 d = e4[(size_t)m3 * 32 + lane];
    acc.x += (a.x + b.x) + (c.x + d.x);
    acc.y += (a.y + b.y) + (c.y + d.y);
    acc.z += (a.z + b.z) + (c.z + d.z);
    acc.w += (a.w + b.w) + (c.w + d.w);
  }
  for (; j < hi; ++j) {
    int m = node_edges[j];
    float4 a = e4[(size_t)m * 32 + lane];
    acc.x += a.x; acc.y += a.y; acc.z += a.z; acc.w += a.w;
  }
  float di = Dinv[n];
  float4 bb = ((const float4*)bias)[lane];
  float4 rv;
  rv.x = fmaxf(di * acc.x + bb.x, 0.f);
  rv.y = fmaxf(di * acc.y + bb.y, 0.f);
  rv.z = fmaxf(di * acc.z + bb.z, 0.f);
  rv.w = fmaxf(di * acc.w + bb.w, 0.f);
  ((float4*)out)[(size_t)n * 32 + lane] = rv;
}

// ---------------- host-side launch ---------------------------------------
extern "C" void kernel_launch(void* const* d_in, const int* in_sizes, int n_in,
                              void* d_out, int out_size, void* d_ws, size_t ws_size,
                              hipStream_t stream) {
  const float* x = (const float*)d_in[0];
  const int* hidx = (const int*)d_in[1];
  const int* node_idx = hidx;        // hyperedge_index[0]
  const int* edge_idx = hidx + EE;   // hyperedge_index[1]
  const float* hw = (const float*)d_in[2];
  // d_in[3] = hyperedge_attr (unused), d_in[4] = batch (unused)
  const float* W1 = (const float*)d_in[5];
  const float* b1 = (const float*)d_in[6];
  const float* W2 = (const float*)d_in[7];
  const float* b2 = (const float*)d_in[8];
  const float* W3 = (const float*)d_in[9];
  const float* b3 = (const float*)d_in[10];
  float* out = (float*)d_out;

  char* ws = (char*)d_ws;
  size_t off = 0;
  auto alloc = [&](size_t bytes) -> char* {
    char* p = ws + off;
    off = align256(off + bytes);
    return p;
  };
  float* xt   = (float*)alloc(sizeof(float) * (size_t)NN * 128);   // 51.2 MB
  float* h    = (float*)alloc(sizeof(float) * (size_t)NN * 128);   // 51.2 MB
  float* ebuf = (float*)alloc(sizeof(float) * (size_t)MM * 128);   // 10.24 MB
  // contiguous zero region: [ecnt MM][efill MM][ncnt NN][nfill NN]
  int*   zr    = (int*)alloc(sizeof(int) * (size_t)(2 * MM + 2 * NN));
  int*   ecnt  = zr;
  int*   efill = zr + MM;
  int*   ncnt  = zr + 2 * MM;
  int*   nfill = zr + 2 * MM + NN;
  int*   eptr  = (int*)alloc(sizeof(int) * (MM + 1));
  int*   nptr  = (int*)alloc(sizeof(int) * (NN + 1));
  float* Binv  = (float*)alloc(sizeof(float) * MM);
  float* Dinv  = (float*)alloc(sizeof(float) * NN);
  int* edge_nodes = (int*)alloc(sizeof(int) * (size_t)EE);         // 6.4 MB
  int* node_edges = (int*)alloc(sizeof(int) * (size_t)EE);         // 6.4 MB
  (void)ws_size; (void)in_sizes; (void)n_in; (void)out_size;

  // IMPORTANT: EE/4 = 400000 is NOT divisible by 256 -> round UP.
  const int quad_grid = (EE / 4 + 255) / 256;

  // ---- graph precompute (once per call; indices are runtime inputs) ----
  zero_i32_kernel<<<512, 256, 0, stream>>>(zr, 2 * MM + 2 * NN);
  count_kernel<<<quad_grid, 256, 0, stream>>>(node_idx, edge_idx, ecnt, ncnt);
  scan_kernel<<<1, 1024, 0, stream>>>(ecnt, MM, eptr, Binv);
  scan_kernel<<<1, 1024, 0, stream>>>(ncnt, NN, nptr, nullptr);
  fill_kernel<<<quad_grid, 256, 0, stream>>>(node_idx, edge_idx, eptr, nptr,
                                             efill, nfill, edge_nodes, node_edges);
  dinv_csr_kernel<<<(NN + 255) / 256, 256, 0, stream>>>(nptr, node_edges, hw, Dinv);

  const int gemm_grid = (NN + 63) / 64;
  const int eagg_grid = MM / 8;   // 20000 % 8 == 0
  const int nagg_grid = NN / 8;   // 100000 % 8 == 0

  // ---- layer 1 ----
  gemm128_kernel<<<gemm_grid, 256, 0, stream>>>(x, W1, xt, NN);
  edge_agg_kernel<<<eagg_grid, 256, 0, stream>>>(xt, eptr, edge_nodes, Binv, ebuf);
  node_agg_kernel<<<nagg_grid, 256, 0, stream>>>(ebuf, nptr, node_edges, Dinv, b1, h);
  // ---- layer 2 ----
  gemm128_kernel<<<gemm_grid, 256, 0, stream>>>(h, W2, xt, NN);
  edge_agg_kernel<<<eagg_grid, 256, 0, stream>>>(xt, eptr, edge_nodes, Binv, ebuf);
  node_agg_kernel<<<nagg_grid, 256, 0, stream>>>(ebuf, nptr, node_edges, Dinv, b2, h);
  // ---- layer 3 ----
  gemm128_kernel<<<gemm_grid, 256, 0, stream>>>(h, W3, xt, NN);
  edge_agg_kernel<<<eagg_grid, 256, 0, stream>>>(xt, eptr, edge_nodes, Binv, ebuf);
  node_agg_kernel<<<nagg_grid, 256, 0, stream>>>(ebuf, nptr, node_edges, Dinv, b3, out);
}

// Round 5
// 957.584 us; speedup vs baseline: 1.4737x; 1.3961x over previous
//
#include <hip/hip_runtime.h>
#include <hip/hip_fp16.h>

#define NN 100000
#define MM 20000
#define EE 1600000
// C = 128 channels. fp16 intermediates: row = 128 half = 256 B = 32x half4.

static inline size_t align256(size_t x) { return (x + 255) & ~(size_t)255; }

struct alignas(8) half4 { __half2 lo, hi; };

__device__ __forceinline__ float4 h4_to_f4(half4 v) {
  float2 a = __half22float2(v.lo);
  float2 b = __half22float2(v.hi);
  return make_float4(a.x, a.y, b.x, b.y);
}
__device__ __forceinline__ half4 f4_to_h4(float4 v) {
  half4 r;
  r.lo = __float22half2_rn(make_float2(v.x, v.y));
  r.hi = __float22half2_rn(make_float2(v.z, v.w));
  return r;
}

// ---------------- zero fill -----------------------------------------------
__global__ void zero_i32_kernel(int* __restrict__ p, int n) {
  int i = blockIdx.x * blockDim.x + threadIdx.x;
  int stride = gridDim.x * blockDim.x;
  for (; i < n; i += stride) p[i] = 0;
}

// ---------------- histogram + rank capture --------------------------------
// 4 incidences/thread; atomicAdd's return value IS the incidence's rank
// within its bucket -> stored packed (coalesced) so fill needs no atomics.
__global__ __launch_bounds__(256) void count_kernel(
    const int* __restrict__ node_idx, const int* __restrict__ edge_idx,
    int* __restrict__ ecnt, int* __restrict__ ncnt,
    unsigned int* __restrict__ rank_packed) {
  int i = blockIdx.x * 256 + threadIdx.x;   // quad index
  if (i >= EE / 4) return;
  int4 nv = ((const int4*)node_idx)[i];
  int4 ev = ((const int4*)edge_idx)[i];
  int n[4] = {nv.x, nv.y, nv.z, nv.w};
  int e[4] = {ev.x, ev.y, ev.z, ev.w};
  unsigned int rp[4];
#pragma unroll
  for (int j = 0; j < 4; ++j) {
    unsigned int p = (unsigned int)atomicAdd(&ecnt[e[j]], 1);
    unsigned int q = (unsigned int)atomicAdd(&ncnt[n[j]], 1);
    rp[j] = (p & 0xFFFFu) | (q << 16);
  }
  ((uint4*)rank_packed)[i] = make_uint4(rp[0], rp[1], rp[2], rp[3]);
}

// ---------------- single-block exclusive scan: cnt[len] -> ptr[len+1] ----
// Optionally writes inv[i] = cnt[i]>0 ? 1/cnt[i] : 0 (B^{-1}).
__global__ __launch_bounds__(1024) void scan_kernel(
    const int* __restrict__ cnt, int len, int* __restrict__ ptr,
    float* __restrict__ inv) {
  __shared__ int lds[1024];
  int t = threadIdx.x;
  int chunk = (len + 1023) >> 10;
  int lo = t * chunk;
  int hi = min(lo + chunk, len);
  int s = 0;
  for (int i = lo; i < hi; ++i) s += cnt[i];
  lds[t] = s;
  __syncthreads();
  for (int d = 1; d < 1024; d <<= 1) {
    int o = (t >= d) ? lds[t - d] : 0;
    __syncthreads();
    lds[t] += o;
    __syncthreads();
  }
  int excl = lds[t] - s;
  int run = excl;
  for (int i = lo; i < hi; ++i) {
    ptr[i] = run;
    int c = cnt[i];
    run += c;
    if (inv) inv[i] = (c > 0) ? 1.0f / (float)c : 0.0f;
  }
  if (t == 1023) ptr[len] = lds[1023];
}

// ---------------- CSR fill: NO atomics (slots from rank_packed) -----------
__global__ __launch_bounds__(256) void fill_kernel(
    const int* __restrict__ node_idx, const int* __restrict__ edge_idx,
    const int* __restrict__ eptr, const int* __restrict__ nptr,
    const unsigned int* __restrict__ rank_packed,
    int* __restrict__ edge_nodes, int* __restrict__ node_edges) {
  int i = blockIdx.x * 256 + threadIdx.x;   // quad index
  if (i >= EE / 4) return;
  int4 nv = ((const int4*)node_idx)[i];
  int4 ev = ((const int4*)edge_idx)[i];
  uint4 rv = ((const uint4*)rank_packed)[i];
  int n[4] = {nv.x, nv.y, nv.z, nv.w};
  int e[4] = {ev.x, ev.y, ev.z, ev.w};
  unsigned int rp[4] = {rv.x, rv.y, rv.z, rv.w};
#pragma unroll
  for (int j = 0; j < 4; ++j) {
    edge_nodes[eptr[e[j]] + (int)(rp[j] & 0xFFFFu)] = n[j];
    node_edges[nptr[n[j]] + (int)(rp[j] >> 16)] = e[j];
  }
}

// ---------------- Dinv from node CSR (no atomics) -------------------------
__global__ __launch_bounds__(256) void dinv_csr_kernel(
    const int* __restrict__ nptr, const int* __restrict__ node_edges,
    const float* __restrict__ hw, float* __restrict__ Dinv) {
  int n = blockIdx.x * 256 + threadIdx.x;
  if (n >= NN) return;
  int lo = nptr[n], hi = nptr[n + 1];
  float d = 0.0f;
  for (int j = lo; j < hi; ++j) d += hw[node_edges[j]];
  Dinv[n] = (d > 0.0f) ? 1.0f / d : 0.0f;
}

// ---------------- fp32-compute GEMM: Y = X @ W, templated I/O types ------
__device__ __forceinline__ void fma4(float4& acc, float s, const float4& m) {
  acc.x += s * m.x;
  acc.y += s * m.y;
  acc.z += s * m.z;
  acc.w += s * m.w;
}
__device__ __forceinline__ float4 ldrow(const float* X, size_t i) {
  return ((const float4*)X)[i];
}
__device__ __forceinline__ float4 ldrow(const __half* X, size_t i) {
  return h4_to_f4(((const half4*)X)[i]);
}
__device__ __forceinline__ void strow(float* Y, size_t i, float4 v) {
  ((float4*)Y)[i] = v;
}
__device__ __forceinline__ void strow(__half* Y, size_t i, float4 v) {
  ((half4*)Y)[i] = f4_to_h4(v);
}

template <typename TIN, typename TOUT>
__global__ __launch_bounds__(256) void gemm128_kernel(
    const TIN* __restrict__ X, const float* __restrict__ W,
    TOUT* __restrict__ Y, int nrows) {
  __shared__ float Wl[128 * 128];
  float4* Wl4 = (float4*)Wl;
  const float4* W4 = (const float4*)W;
  for (int i = threadIdx.x; i < 128 * 32; i += 256) Wl4[i] = W4[i];
  __syncthreads();

  int tc = threadIdx.x & 15;   // 16 column threads (4ch at 4*tc and 64+4*tc)
  int tr = threadIdx.x >> 4;   // 16 row threads
  int base = blockIdx.x * 64;
  int r[4];
  bool v[4];
#pragma unroll
  for (int j = 0; j < 4; ++j) {
    int rr = base + tr + j * 16;
    v[j] = rr < nrows;
    r[j] = v[j] ? rr : 0;
  }
  float4 acc[4][2];
#pragma unroll
  for (int j = 0; j < 4; ++j) {
    acc[j][0] = make_float4(0.f, 0.f, 0.f, 0.f);
    acc[j][1] = make_float4(0.f, 0.f, 0.f, 0.f);
  }
#pragma unroll 4
  for (int k4 = 0; k4 < 32; ++k4) {
    float4 xv[4];
#pragma unroll
    for (int j = 0; j < 4; ++j) xv[j] = ldrow(X, (size_t)r[j] * 32 + k4);
#pragma unroll
    for (int kk = 0; kk < 4; ++kk) {
      float4 wva = Wl4[(k4 * 4 + kk) * 32 + tc];
      float4 wvb = Wl4[(k4 * 4 + kk) * 32 + 16 + tc];
#pragma unroll
      for (int j = 0; j < 4; ++j) {
        float xk = ((const float*)&xv[j])[kk];
        fma4(acc[j][0], xk, wva);
        fma4(acc[j][1], xk, wvb);
      }
    }
  }
#pragma unroll
  for (int j = 0; j < 4; ++j) {
    if (v[j]) {
      strow(Y, (size_t)r[j] * 32 + tc, acc[j][0]);
      strow(Y, (size_t)r[j] * 32 + 16 + tc, acc[j][1]);
    }
  }
}

// ---------------- edge aggregation: e[m] = Binv[m] * sum xt[members] -----
// half-wave (32 lanes x 4ch fp16 = 128 ch) per edge; unroll-4 over members.
__global__ __launch_bounds__(256) void edge_agg_kernel(
    const __half* __restrict__ xt, const int* __restrict__ eptr,
    const int* __restrict__ edge_nodes, const float* __restrict__ Binv,
    __half* __restrict__ eout) {
  int half_id = threadIdx.x >> 5;
  int lane = threadIdx.x & 31;
  int m = blockIdx.x * 8 + half_id;
  if (m >= MM) return;
  int lo = eptr[m], hi = eptr[m + 1];
  const half4* xt4 = (const half4*)xt;
  float4 acc = make_float4(0.f, 0.f, 0.f, 0.f);
  int j = lo;
  for (; j + 4 <= hi; j += 4) {
    int n0 = edge_nodes[j + 0];
    int n1 = edge_nodes[j + 1];
    int n2 = edge_nodes[j + 2];
    int n3 = edge_nodes[j + 3];
    float4 a = h4_to_f4(xt4[(size_t)n0 * 32 + lane]);
    float4 b = h4_to_f4(xt4[(size_t)n1 * 32 + lane]);
    float4 c = h4_to_f4(xt4[(size_t)n2 * 32 + lane]);
    float4 d = h4_to_f4(xt4[(size_t)n3 * 32 + lane]);
    acc.x += (a.x + b.x) + (c.x + d.x);
    acc.y += (a.y + b.y) + (c.y + d.y);
    acc.z += (a.z + b.z) + (c.z + d.z);
    acc.w += (a.w + b.w) + (c.w + d.w);
  }
  for (; j < hi; ++j) {
    int n = edge_nodes[j];
    float4 a = h4_to_f4(xt4[(size_t)n * 32 + lane]);
    acc.x += a.x; acc.y += a.y; acc.z += a.z; acc.w += a.w;
  }
  float bi = Binv[m];
  acc.x *= bi; acc.y *= bi; acc.z *= bi; acc.w *= bi;
  ((half4*)eout)[(size_t)m * 32 + lane] = f4_to_h4(acc);
}

// ---------------- node aggregation + bias + relu, templated output -------
template <typename TOUT>
__global__ __launch_bounds__(256) void node_agg_kernel(
    const __half* __restrict__ ein, const int* __restrict__ nptr,
    const int* __restrict__ node_edges, const float* __restrict__ Dinv,
    const float* __restrict__ bias, TOUT* __restrict__ out) {
  int half_id = threadIdx.x >> 5;
  int lane = threadIdx.x & 31;
  int n = blockIdx.x * 8 + half_id;
  if (n >= NN) return;
  int lo = nptr[n], hi = nptr[n + 1];
  const half4* e4 = (const half4*)ein;
  float4 acc = make_float4(0.f, 0.f, 0.f, 0.f);
  int j = lo;
  for (; j + 4 <= hi; j += 4) {
    int m0 = node_edges[j + 0];
    int m1 = node_edges[j + 1];
    int m2 = node_edges[j + 2];
    int m3 = node_edges[j + 3];
    float4 a = h4_to_f4(e4[(size_t)m0 * 32 + lane]);
    float4 b = h4_to_f4(e4[(size_t)m1 * 32 + lane]);
    float4 c = h4_to_f4(e4[(size_t)m2 * 32 + lane]);
    float4 d = h4_to_f4(e4[(size_t)m3 * 32 + lane]);
    acc.x += (a.x + b.x) + (c.x + d.x);
    acc.y += (a.y + b.y) + (c.y + d.y);
    acc.z += (a.z + b.z) + (c.z + d.z);
    acc.w += (a.w + b.w) + (c.w + d.w);
  }
  for (; j < hi; ++j) {
    int m = node_edges[j];
    float4 a = h4_to_f4(e4[(size_t)m * 32 + lane]);
    acc.x += a.x; acc.y += a.y; acc.z += a.z; acc.w += a.w;
  }
  float di = Dinv[n];
  float4 bb = ((const float4*)bias)[lane];
  float4 rv;
  rv.x = fmaxf(di * acc.x + bb.x, 0.f);
  rv.y = fmaxf(di * acc.y + bb.y, 0.f);
  rv.z = fmaxf(di * acc.z + bb.z, 0.f);
  rv.w = fmaxf(di * acc.w + bb.w, 0.f);
  strow(out, (size_t)n * 32 + lane, rv);
}

// ---------------- host-side launch ---------------------------------------
extern "C" void kernel_launch(void* const* d_in, const int* in_sizes, int n_in,
                              void* d_out, int out_size, void* d_ws, size_t ws_size,
                              hipStream_t stream) {
  const float* x = (const float*)d_in[0];
  const int* hidx = (const int*)d_in[1];
  const int* node_idx = hidx;        // hyperedge_index[0]
  const int* edge_idx = hidx + EE;   // hyperedge_index[1]
  const float* hw = (const float*)d_in[2];
  // d_in[3] = hyperedge_attr (unused), d_in[4] = batch (unused)
  const float* W1 = (const float*)d_in[5];
  const float* b1 = (const float*)d_in[6];
  const float* W2 = (const float*)d_in[7];
  const float* b2 = (const float*)d_in[8];
  const float* W3 = (const float*)d_in[9];
  const float* b3 = (const float*)d_in[10];
  float* out = (float*)d_out;

  char* ws = (char*)d_ws;
  size_t off = 0;
  auto alloc = [&](size_t bytes) -> char* {
    char* p = ws + off;
    off = align256(off + bytes);
    return p;
  };
  __half* xt   = (__half*)alloc(sizeof(__half) * (size_t)NN * 128);  // 25.6 MB
  __half* h    = (__half*)alloc(sizeof(__half) * (size_t)NN * 128);  // 25.6 MB
  __half* ebuf = (__half*)alloc(sizeof(__half) * (size_t)MM * 128);  // 5.12 MB
  // contiguous zero region: [ecnt MM][ncnt NN]
  int*   zr    = (int*)alloc(sizeof(int) * (size_t)(MM + NN));
  int*   ecnt  = zr;
  int*   ncnt  = zr + MM;
  int*   eptr  = (int*)alloc(sizeof(int) * (MM + 1));
  int*   nptr  = (int*)alloc(sizeof(int) * (NN + 1));
  float* Binv  = (float*)alloc(sizeof(float) * MM);
  float* Dinv  = (float*)alloc(sizeof(float) * NN);
  unsigned int* rank_packed = (unsigned int*)alloc(sizeof(int) * (size_t)EE);
  int* edge_nodes = (int*)alloc(sizeof(int) * (size_t)EE);           // 6.4 MB
  int* node_edges = (int*)alloc(sizeof(int) * (size_t)EE);           // 6.4 MB
  (void)ws_size; (void)in_sizes; (void)n_in; (void)out_size;

  // EE/4 = 400000 is NOT divisible by 256 -> round UP (guard in kernels).
  const int quad_grid = (EE / 4 + 255) / 256;

  // ---- graph precompute (once per call; indices are runtime inputs) ----
  zero_i32_kernel<<<256, 256, 0, stream>>>(zr, MM + NN);
  count_kernel<<<quad_grid, 256, 0, stream>>>(node_idx, edge_idx, ecnt, ncnt,
                                              rank_packed);
  scan_kernel<<<1, 1024, 0, stream>>>(ecnt, MM, eptr, Binv);
  scan_kernel<<<1, 1024, 0, stream>>>(ncnt, NN, nptr, nullptr);
  fill_kernel<<<quad_grid, 256, 0, stream>>>(node_idx, edge_idx, eptr, nptr,
                                             rank_packed, edge_nodes, node_edges);
  dinv_csr_kernel<<<(NN + 255) / 256, 256, 0, stream>>>(nptr, node_edges, hw, Dinv);

  const int gemm_grid = (NN + 63) / 64;
  const int eagg_grid = MM / 8;   // 20000 % 8 == 0
  const int nagg_grid = NN / 8;   // 100000 % 8 == 0

  // ---- layer 1 ----
  gemm128_kernel<float, __half><<<gemm_grid, 256, 0, stream>>>(x, W1, xt, NN);
  edge_agg_kernel<<<eagg_grid, 256, 0, stream>>>(xt, eptr, edge_nodes, Binv, ebuf);
  node_agg_kernel<__half><<<nagg_grid, 256, 0, stream>>>(ebuf, nptr, node_edges,
                                                         Dinv, b1, h);
  // ---- layer 2 ----
  gemm128_kernel<__half, __half><<<gemm_grid, 256, 0, stream>>>(h, W2, xt, NN);
  edge_agg_kernel<<<eagg_grid, 256, 0, stream>>>(xt, eptr, edge_nodes, Binv, ebuf);
  node_agg_kernel<__half><<<nagg_grid, 256, 0, stream>>>(ebuf, nptr, node_edges,
                                                         Dinv, b2, h);
  // ---- layer 3 ----
  gemm128_kernel<__half, __half><<<gemm_grid, 256, 0, stream>>>(h, W3, xt, NN);
  edge_agg_kernel<<<eagg_grid, 256, 0, stream>>>(xt, eptr, edge_nodes, Binv, ebuf);
  node_agg_kernel<float><<<nagg_grid, 256, 0, stream>>>(ebuf, nptr, node_edges,
                                                        Dinv, b3, out);
}

// Round 6
// 775.057 us; speedup vs baseline: 1.8208x; 1.2355x over previous
//
#include <hip/hip_runtime.h>
#include <hip/hip_fp16.h>

#define NN 100000
#define MM 20000
#define EE 1600000
// C = 128 channels. fp16 intermediates: row = 128 half = 256 B = 32x half4.

#define SCAN_BLOCK 256
#define SCAN_ITEMS 8
#define SCAN_TILE (SCAN_BLOCK * SCAN_ITEMS)          // 2048
#define NB_E ((MM + SCAN_TILE - 1) / SCAN_TILE)      // 10
#define NB_N ((NN + SCAN_TILE - 1) / SCAN_TILE)      // 49
#define NB_TOT (NB_E + NB_N)                         // 59

static inline size_t align256(size_t x) { return (x + 255) & ~(size_t)255; }

struct alignas(8) half4 { __half2 lo, hi; };

__device__ __forceinline__ float4 h4_to_f4(half4 v) {
  float2 a = __half22float2(v.lo);
  float2 b = __half22float2(v.hi);
  return make_float4(a.x, a.y, b.x, b.y);
}
__device__ __forceinline__ half4 f4_to_h4(float4 v) {
  half4 r;
  r.lo = __float22half2_rn(make_float2(v.x, v.y));
  r.hi = __float22half2_rn(make_float2(v.z, v.w));
  return r;
}

// ---------------- zero fill -----------------------------------------------
__global__ void zero_i32_kernel(int* __restrict__ p, int n) {
  int i = blockIdx.x * blockDim.x + threadIdx.x;
  int stride = gridDim.x * blockDim.x;
  for (; i < n; i += stride) p[i] = 0;
}

// ---------------- histogram + rank capture --------------------------------
// 4 incidences/thread; atomicAdd's return value IS the incidence's rank
// within its bucket -> stored packed (coalesced) so fill needs no atomics.
__global__ __launch_bounds__(256) void count_kernel(
    const int* __restrict__ node_idx, const int* __restrict__ edge_idx,
    int* __restrict__ ecnt, int* __restrict__ ncnt,
    unsigned int* __restrict__ rank_packed) {
  int i = blockIdx.x * 256 + threadIdx.x;   // quad index
  if (i >= EE / 4) return;
  int4 nv = ((const int4*)node_idx)[i];
  int4 ev = ((const int4*)edge_idx)[i];
  int n[4] = {nv.x, nv.y, nv.z, nv.w};
  int e[4] = {ev.x, ev.y, ev.z, ev.w};
  unsigned int rp[4];
#pragma unroll
  for (int j = 0; j < 4; ++j) {
    unsigned int p = (unsigned int)atomicAdd(&ecnt[e[j]], 1);
    unsigned int q = (unsigned int)atomicAdd(&ncnt[n[j]], 1);
    rp[j] = (p & 0xFFFFu) | (q << 16);
  }
  ((uint4*)rank_packed)[i] = make_uint4(rp[0], rp[1], rp[2], rp[3]);
}

// ---------------- hierarchical scan (both arrays in one 3-dispatch pass) --
// Segment 0: ecnt[MM] -> eptr (blocks 0..NB_E-1)
// Segment 1: ncnt[NN] -> nptr (blocks NB_E..NB_TOT-1)
__global__ __launch_bounds__(SCAN_BLOCK) void scan_partial_kernel(
    const int* __restrict__ ecnt, const int* __restrict__ ncnt,
    int* __restrict__ eptr, int* __restrict__ nptr, int* __restrict__ bsum) {
  __shared__ int lds[SCAN_BLOCK];
  int b = blockIdx.x;
  const int* cnt; int* ptr; int len; int lb;
  if (b < NB_E) { cnt = ecnt; ptr = eptr; len = MM; lb = b; }
  else          { cnt = ncnt; ptr = nptr; len = NN; lb = b - NB_E; }
  int t = threadIdx.x;
  int lo = lb * SCAN_TILE + t * SCAN_ITEMS;
  int v[SCAN_ITEMS];
  int s = 0;
#pragma unroll
  for (int j = 0; j < SCAN_ITEMS; ++j) {
    int idx = lo + j;
    v[j] = (idx < len) ? cnt[idx] : 0;
    s += v[j];
  }
  lds[t] = s;
  __syncthreads();
  for (int d = 1; d < SCAN_BLOCK; d <<= 1) {
    int o = (t >= d) ? lds[t - d] : 0;
    __syncthreads();
    lds[t] += o;
    __syncthreads();
  }
  int run = lds[t] - s;   // exclusive prefix within block
#pragma unroll
  for (int j = 0; j < SCAN_ITEMS; ++j) {
    int idx = lo + j;
    if (idx < len) ptr[idx] = run;
    run += v[j];
  }
  if (t == SCAN_BLOCK - 1) bsum[b] = lds[t];
}

__global__ void scan_bsum_kernel(int* __restrict__ bsum) {
  int t = threadIdx.x;
  if (t == 0) {
    int run = 0;
    for (int i = 0; i < NB_E; ++i) { int c = bsum[i]; bsum[i] = run; run += c; }
  } else if (t == 1) {
    int run = 0;
    for (int i = NB_E; i < NB_TOT; ++i) { int c = bsum[i]; bsum[i] = run; run += c; }
  }
}

__global__ __launch_bounds__(SCAN_BLOCK) void scan_fixup_kernel(
    int* __restrict__ eptr, int* __restrict__ nptr,
    const int* __restrict__ ecnt, const int* __restrict__ bsum,
    float* __restrict__ Binv) {
  int b = blockIdx.x;
  int* ptr; int len; int lb; bool isE;
  if (b < NB_E) { ptr = eptr; len = MM; lb = b; isE = true; }
  else          { ptr = nptr; len = NN; lb = b - NB_E; isE = false; }
  int boff = bsum[b];
  int t = threadIdx.x;
  int lo = lb * SCAN_TILE + t * SCAN_ITEMS;
#pragma unroll
  for (int j = 0; j < SCAN_ITEMS; ++j) {
    int idx = lo + j;
    if (idx < len) {
      ptr[idx] += boff;
      if (isE) {
        int c = ecnt[idx];
        Binv[idx] = (c > 0) ? 1.0f / (float)c : 0.0f;
      }
    }
  }
  // totals are the constant EE (each incidence counted once per histogram)
  if (b == 0 && t == 0) { eptr[MM] = EE; nptr[NN] = EE; }
}

// ---------------- CSR fill: NO atomics (slots from rank_packed) -----------
__global__ __launch_bounds__(256) void fill_kernel(
    const int* __restrict__ node_idx, const int* __restrict__ edge_idx,
    const int* __restrict__ eptr, const int* __restrict__ nptr,
    const unsigned int* __restrict__ rank_packed,
    int* __restrict__ edge_nodes, int* __restrict__ node_edges) {
  int i = blockIdx.x * 256 + threadIdx.x;   // quad index
  if (i >= EE / 4) return;
  int4 nv = ((const int4*)node_idx)[i];
  int4 ev = ((const int4*)edge_idx)[i];
  uint4 rv = ((const uint4*)rank_packed)[i];
  int n[4] = {nv.x, nv.y, nv.z, nv.w};
  int e[4] = {ev.x, ev.y, ev.z, ev.w};
  unsigned int rp[4] = {rv.x, rv.y, rv.z, rv.w};
#pragma unroll
  for (int j = 0; j < 4; ++j) {
    edge_nodes[eptr[e[j]] + (int)(rp[j] & 0xFFFFu)] = n[j];
    node_edges[nptr[n[j]] + (int)(rp[j] >> 16)] = e[j];
  }
}

// ---------------- Dinv from node CSR (no atomics) -------------------------
__global__ __launch_bounds__(256) void dinv_csr_kernel(
    const int* __restrict__ nptr, const int* __restrict__ node_edges,
    const float* __restrict__ hw, float* __restrict__ Dinv) {
  int n = blockIdx.x * 256 + threadIdx.x;
  if (n >= NN) return;
  int lo = nptr[n], hi = nptr[n + 1];
  float d = 0.0f;
  for (int j = lo; j < hi; ++j) d += hw[node_edges[j]];
  Dinv[n] = (d > 0.0f) ? 1.0f / d : 0.0f;
}

// ---------------- fp32-compute GEMM: Y = X @ W, templated I/O types ------
__device__ __forceinline__ void fma4(float4& acc, float s, const float4& m) {
  acc.x += s * m.x;
  acc.y += s * m.y;
  acc.z += s * m.z;
  acc.w += s * m.w;
}
__device__ __forceinline__ float4 ldrow(const float* X, size_t i) {
  return ((const float4*)X)[i];
}
__device__ __forceinline__ float4 ldrow(const __half* X, size_t i) {
  return h4_to_f4(((const half4*)X)[i]);
}
__device__ __forceinline__ void strow(float* Y, size_t i, float4 v) {
  ((float4*)Y)[i] = v;
}
__device__ __forceinline__ void strow(__half* Y, size_t i, float4 v) {
  ((half4*)Y)[i] = f4_to_h4(v);
}

template <typename TIN, typename TOUT>
__global__ __launch_bounds__(256) void gemm128_kernel(
    const TIN* __restrict__ X, const float* __restrict__ W,
    TOUT* __restrict__ Y, int nrows) {
  __shared__ float Wl[128 * 128];
  float4* Wl4 = (float4*)Wl;
  const float4* W4 = (const float4*)W;
  for (int i = threadIdx.x; i < 128 * 32; i += 256) Wl4[i] = W4[i];
  __syncthreads();

  int tc = threadIdx.x & 15;   // 16 column threads
  int tr = threadIdx.x >> 4;   // 16 row threads
  int base = blockIdx.x * 64;
  int r[4];
  bool v[4];
#pragma unroll
  for (int j = 0; j < 4; ++j) {
    int rr = base + tr + j * 16;
    v[j] = rr < nrows;
    r[j] = v[j] ? rr : 0;
  }
  float4 acc[4][2];
#pragma unroll
  for (int j = 0; j < 4; ++j) {
    acc[j][0] = make_float4(0.f, 0.f, 0.f, 0.f);
    acc[j][1] = make_float4(0.f, 0.f, 0.f, 0.f);
  }
#pragma unroll 4
  for (int k4 = 0; k4 < 32; ++k4) {
    float4 xv[4];
#pragma unroll
    for (int j = 0; j < 4; ++j) xv[j] = ldrow(X, (size_t)r[j] * 32 + k4);
#pragma unroll
    for (int kk = 0; kk < 4; ++kk) {
      float4 wva = Wl4[(k4 * 4 + kk) * 32 + tc];
      float4 wvb = Wl4[(k4 * 4 + kk) * 32 + 16 + tc];
#pragma unroll
      for (int j = 0; j < 4; ++j) {
        float xk = ((const float*)&xv[j])[kk];
        fma4(acc[j][0], xk, wva);
        fma4(acc[j][1], xk, wvb);
      }
    }
  }
#pragma unroll
  for (int j = 0; j < 4; ++j) {
    if (v[j]) {
      strow(Y, (size_t)r[j] * 32 + tc, acc[j][0]);
      strow(Y, (size_t)r[j] * 32 + 16 + tc, acc[j][1]);
    }
  }
}

// ---------------- edge aggregation: e[m] = Binv[m] * sum xt[members] -----
__global__ __launch_bounds__(256) void edge_agg_kernel(
    const __half* __restrict__ xt, const int* __restrict__ eptr,
    const int* __restrict__ edge_nodes, const float* __restrict__ Binv,
    __half* __restrict__ eout) {
  int half_id = threadIdx.x >> 5;
  int lane = threadIdx.x & 31;
  int m = blockIdx.x * 8 + half_id;
  if (m >= MM) return;
  int lo = eptr[m], hi = eptr[m + 1];
  const half4* xt4 = (const half4*)xt;
  float4 acc = make_float4(0.f, 0.f, 0.f, 0.f);
  int j = lo;
  for (; j + 4 <= hi; j += 4) {
    int n0 = edge_nodes[j + 0];
    int n1 = edge_nodes[j + 1];
    int n2 = edge_nodes[j + 2];
    int n3 = edge_nodes[j + 3];
    float4 a = h4_to_f4(xt4[(size_t)n0 * 32 + lane]);
    float4 b = h4_to_f4(xt4[(size_t)n1 * 32 + lane]);
    float4 c = h4_to_f4(xt4[(size_t)n2 * 32 + lane]);
    float4 d = h4_to_f4(xt4[(size_t)n3 * 32 + lane]);
    acc.x += (a.x + b.x) + (c.x + d.x);
    acc.y += (a.y + b.y) + (c.y + d.y);
    acc.z += (a.z + b.z) + (c.z + d.z);
    acc.w += (a.w + b.w) + (c.w + d.w);
  }
  for (; j < hi; ++j) {
    int n = edge_nodes[j];
    float4 a = h4_to_f4(xt4[(size_t)n * 32 + lane]);
    acc.x += a.x; acc.y += a.y; acc.z += a.z; acc.w += a.w;
  }
  float bi = Binv[m];
  acc.x *= bi; acc.y *= bi; acc.z *= bi; acc.w *= bi;
  ((half4*)eout)[(size_t)m * 32 + lane] = f4_to_h4(acc);
}

// ---------------- node aggregation + bias + relu, templated output -------
template <typename TOUT>
__global__ __launch_bounds__(256) void node_agg_kernel(
    const __half* __restrict__ ein, const int* __restrict__ nptr,
    const int* __restrict__ node_edges, const float* __restrict__ Dinv,
    const float* __restrict__ bias, TOUT* __restrict__ out) {
  int half_id = threadIdx.x >> 5;
  int lane = threadIdx.x & 31;
  int n = blockIdx.x * 8 + half_id;
  if (n >= NN) return;
  int lo = nptr[n], hi = nptr[n + 1];
  const half4* e4 = (const half4*)ein;
  float4 acc = make_float4(0.f, 0.f, 0.f, 0.f);
  int j = lo;
  for (; j + 4 <= hi; j += 4) {
    int m0 = node_edges[j + 0];
    int m1 = node_edges[j + 1];
    int m2 = node_edges[j + 2];
    int m3 = node_edges[j + 3];
    float4 a = h4_to_f4(e4[(size_t)m0 * 32 + lane]);
    float4 b = h4_to_f4(e4[(size_t)m1 * 32 + lane]);
    float4 c = h4_to_f4(e4[(size_t)m2 * 32 + lane]);
    float4 d = h4_to_f4(e4[(size_t)m3 * 32 + lane]);
    acc.x += (a.x + b.x) + (c.x + d.x);
    acc.y += (a.y + b.y) + (c.y + d.y);
    acc.z += (a.z + b.z) + (c.z + d.z);
    acc.w += (a.w + b.w) + (c.w + d.w);
  }
  for (; j < hi; ++j) {
    int m = node_edges[j];
    float4 a = h4_to_f4(e4[(size_t)m * 32 + lane]);
    acc.x += a.x; acc.y += a.y; acc.z += a.z; acc.w += a.w;
  }
  float di = Dinv[n];
  float4 bb = ((const float4*)bias)[lane];
  float4 rv;
  rv.x = fmaxf(di * acc.x + bb.x, 0.f);
  rv.y = fmaxf(di * acc.y + bb.y, 0.f);
  rv.z = fmaxf(di * acc.z + bb.z, 0.f);
  rv.w = fmaxf(di * acc.w + bb.w, 0.f);
  strow(out, (size_t)n * 32 + lane, rv);
}

// ---------------- host-side launch ---------------------------------------
extern "C" void kernel_launch(void* const* d_in, const int* in_sizes, int n_in,
                              void* d_out, int out_size, void* d_ws, size_t ws_size,
                              hipStream_t stream) {
  const float* x = (const float*)d_in[0];
  const int* hidx = (const int*)d_in[1];
  const int* node_idx = hidx;        // hyperedge_index[0]
  const int* edge_idx = hidx + EE;   // hyperedge_index[1]
  const float* hw = (const float*)d_in[2];
  // d_in[3] = hyperedge_attr (unused), d_in[4] = batch (unused)
  const float* W1 = (const float*)d_in[5];
  const float* b1 = (const float*)d_in[6];
  const float* W2 = (const float*)d_in[7];
  const float* b2 = (const float*)d_in[8];
  const float* W3 = (const float*)d_in[9];
  const float* b3 = (const float*)d_in[10];
  float* out = (float*)d_out;

  char* ws = (char*)d_ws;
  size_t off = 0;
  auto alloc = [&](size_t bytes) -> char* {
    char* p = ws + off;
    off = align256(off + bytes);
    return p;
  };
  __half* xt   = (__half*)alloc(sizeof(__half) * (size_t)NN * 128);  // 25.6 MB
  __half* h    = (__half*)alloc(sizeof(__half) * (size_t)NN * 128);  // 25.6 MB
  __half* ebuf = (__half*)alloc(sizeof(__half) * (size_t)MM * 128);  // 5.12 MB
  // contiguous zero region: [ecnt MM][ncnt NN]
  int*   zr    = (int*)alloc(sizeof(int) * (size_t)(MM + NN));
  int*   ecnt  = zr;
  int*   ncnt  = zr + MM;
  int*   eptr  = (int*)alloc(sizeof(int) * (MM + 1));
  int*   nptr  = (int*)alloc(sizeof(int) * (NN + 1));
  int*   bsum  = (int*)alloc(sizeof(int) * NB_TOT);
  float* Binv  = (float*)alloc(sizeof(float) * MM);
  float* Dinv  = (float*)alloc(sizeof(float) * NN);
  unsigned int* rank_packed = (unsigned int*)alloc(sizeof(int) * (size_t)EE);
  int* edge_nodes = (int*)alloc(sizeof(int) * (size_t)EE);           // 6.4 MB
  int* node_edges = (int*)alloc(sizeof(int) * (size_t)EE);           // 6.4 MB
  (void)ws_size; (void)in_sizes; (void)n_in; (void)out_size;

  // EE/4 = 400000 is NOT divisible by 256 -> round UP (guard in kernels).
  const int quad_grid = (EE / 4 + 255) / 256;

  // ---- graph precompute (once per call; indices are runtime inputs) ----
  zero_i32_kernel<<<256, 256, 0, stream>>>(zr, MM + NN);
  count_kernel<<<quad_grid, 256, 0, stream>>>(node_idx, edge_idx, ecnt, ncnt,
                                              rank_packed);
  scan_partial_kernel<<<NB_TOT, SCAN_BLOCK, 0, stream>>>(ecnt, ncnt, eptr, nptr, bsum);
  scan_bsum_kernel<<<1, 64, 0, stream>>>(bsum);
  scan_fixup_kernel<<<NB_TOT, SCAN_BLOCK, 0, stream>>>(eptr, nptr, ecnt, bsum, Binv);
  fill_kernel<<<quad_grid, 256, 0, stream>>>(node_idx, edge_idx, eptr, nptr,
                                             rank_packed, edge_nodes, node_edges);
  dinv_csr_kernel<<<(NN + 255) / 256, 256, 0, stream>>>(nptr, node_edges, hw, Dinv);

  const int gemm_grid = (NN + 63) / 64;
  const int eagg_grid = MM / 8;   // 20000 % 8 == 0
  const int nagg_grid = NN / 8;   // 100000 % 8 == 0

  // ---- layer 1 ----
  gemm128_kernel<float, __half><<<gemm_grid, 256, 0, stream>>>(x, W1, xt, NN);
  edge_agg_kernel<<<eagg_grid, 256, 0, stream>>>(xt, eptr, edge_nodes, Binv, ebuf);
  node_agg_kernel<__half><<<nagg_grid, 256, 0, stream>>>(ebuf, nptr, node_edges,
                                                         Dinv, b1, h);
  // ---- layer 2 ----
  gemm128_kernel<__half, __half><<<gemm_grid, 256, 0, stream>>>(h, W2, xt, NN);
  edge_agg_kernel<<<eagg_grid, 256, 0, stream>>>(xt, eptr, edge_nodes, Binv, ebuf);
  node_agg_kernel<__half><<<nagg_grid, 256, 0, stream>>>(ebuf, nptr, node_edges,
                                                         Dinv, b2, h);
  // ---- layer 3 ----
  gemm128_kernel<__half, __half><<<gemm_grid, 256, 0, stream>>>(h, W3, xt, NN);
  edge_agg_kernel<<<eagg_grid, 256, 0, stream>>>(xt, eptr, edge_nodes, Binv, ebuf);
  node_agg_kernel<float><<<nagg_grid, 256, 0, stream>>>(ebuf, nptr, node_edges,
                                                        Dinv, b3, out);
}

// Round 7
// 629.405 us; speedup vs baseline: 2.2422x; 1.2314x over previous
//
#include <hip/hip_runtime.h>
#include <hip/hip_fp16.h>

#define NN 100000
#define MM 20000
#define EE 1600000
// C = 128 channels. fp16 intermediates: row = 128 half = 256 B = 32x half4.
// Weight multiply is DEFERRED to the hyperedge side (20k rows, not 100k):
//   X' = D^-1 H B^-1 H^T X Theta  ==  D^-1 H ( (B^-1 H^T X) Theta )

#define SCAN_BLOCK 256
#define SCAN_ITEMS 8
#define SCAN_TILE (SCAN_BLOCK * SCAN_ITEMS)          // 2048
#define NB_E ((MM + SCAN_TILE - 1) / SCAN_TILE)      // 10
#define NB_N ((NN + SCAN_TILE - 1) / SCAN_TILE)      // 49
#define NB_TOT (NB_E + NB_N)                         // 59

static inline size_t align256(size_t x) { return (x + 255) & ~(size_t)255; }

struct alignas(8) half4 { __half2 lo, hi; };

__device__ __forceinline__ float4 h4_to_f4(half4 v) {
  float2 a = __half22float2(v.lo);
  float2 b = __half22float2(v.hi);
  return make_float4(a.x, a.y, b.x, b.y);
}
__device__ __forceinline__ half4 f4_to_h4(float4 v) {
  half4 r;
  r.lo = __float22half2_rn(make_float2(v.x, v.y));
  r.hi = __float22half2_rn(make_float2(v.z, v.w));
  return r;
}

// ---------------- zero fill -----------------------------------------------
__global__ void zero_i32_kernel(int* __restrict__ p, int n) {
  int i = blockIdx.x * blockDim.x + threadIdx.x;
  int stride = gridDim.x * blockDim.x;
  for (; i < n; i += stride) p[i] = 0;
}

// ---------------- fp32 -> fp16 convert (x, once) --------------------------
__global__ __launch_bounds__(256) void cvt_f2h_kernel(
    const float* __restrict__ in, __half* __restrict__ out, int n4) {
  int i = blockIdx.x * 256 + threadIdx.x;
  int stride = gridDim.x * 256;
  for (; i < n4; i += stride) {
    float4 v = ((const float4*)in)[i];
    ((half4*)out)[i] = f4_to_h4(v);
  }
}

// ---------------- histogram + rank capture --------------------------------
// 4 incidences/thread; atomicAdd's return value IS the incidence's rank
// within its bucket -> stored packed (coalesced) so fill needs no atomics.
__global__ __launch_bounds__(256) void count_kernel(
    const int* __restrict__ node_idx, const int* __restrict__ edge_idx,
    int* __restrict__ ecnt, int* __restrict__ ncnt,
    unsigned int* __restrict__ rank_packed) {
  int i = blockIdx.x * 256 + threadIdx.x;   // quad index
  if (i >= EE / 4) return;
  int4 nv = ((const int4*)node_idx)[i];
  int4 ev = ((const int4*)edge_idx)[i];
  int n[4] = {nv.x, nv.y, nv.z, nv.w};
  int e[4] = {ev.x, ev.y, ev.z, ev.w};
  unsigned int rp[4];
#pragma unroll
  for (int j = 0; j < 4; ++j) {
    unsigned int p = (unsigned int)atomicAdd(&ecnt[e[j]], 1);
    unsigned int q = (unsigned int)atomicAdd(&ncnt[n[j]], 1);
    rp[j] = (p & 0xFFFFu) | (q << 16);
  }
  ((uint4*)rank_packed)[i] = make_uint4(rp[0], rp[1], rp[2], rp[3]);
}

// ---------------- hierarchical scan (both arrays in one 3-dispatch pass) --
__global__ __launch_bounds__(SCAN_BLOCK) void scan_partial_kernel(
    const int* __restrict__ ecnt, const int* __restrict__ ncnt,
    int* __restrict__ eptr, int* __restrict__ nptr, int* __restrict__ bsum) {
  __shared__ int lds[SCAN_BLOCK];
  int b = blockIdx.x;
  const int* cnt; int* ptr; int len; int lb;
  if (b < NB_E) { cnt = ecnt; ptr = eptr; len = MM; lb = b; }
  else          { cnt = ncnt; ptr = nptr; len = NN; lb = b - NB_E; }
  int t = threadIdx.x;
  int lo = lb * SCAN_TILE + t * SCAN_ITEMS;
  int v[SCAN_ITEMS];
  int s = 0;
#pragma unroll
  for (int j = 0; j < SCAN_ITEMS; ++j) {
    int idx = lo + j;
    v[j] = (idx < len) ? cnt[idx] : 0;
    s += v[j];
  }
  lds[t] = s;
  __syncthreads();
  for (int d = 1; d < SCAN_BLOCK; d <<= 1) {
    int o = (t >= d) ? lds[t - d] : 0;
    __syncthreads();
    lds[t] += o;
    __syncthreads();
  }
  int run = lds[t] - s;   // exclusive prefix within block
#pragma unroll
  for (int j = 0; j < SCAN_ITEMS; ++j) {
    int idx = lo + j;
    if (idx < len) ptr[idx] = run;
    run += v[j];
  }
  if (t == SCAN_BLOCK - 1) bsum[b] = lds[t];
}

__global__ void scan_bsum_kernel(int* __restrict__ bsum) {
  int t = threadIdx.x;
  if (t == 0) {
    int run = 0;
    for (int i = 0; i < NB_E; ++i) { int c = bsum[i]; bsum[i] = run; run += c; }
  } else if (t == 1) {
    int run = 0;
    for (int i = NB_E; i < NB_TOT; ++i) { int c = bsum[i]; bsum[i] = run; run += c; }
  }
}

__global__ __launch_bounds__(SCAN_BLOCK) void scan_fixup_kernel(
    int* __restrict__ eptr, int* __restrict__ nptr,
    const int* __restrict__ ecnt, const int* __restrict__ bsum,
    float* __restrict__ Binv) {
  int b = blockIdx.x;
  int* ptr; int len; int lb; bool isE;
  if (b < NB_E) { ptr = eptr; len = MM; lb = b; isE = true; }
  else          { ptr = nptr; len = NN; lb = b - NB_E; isE = false; }
  int boff = bsum[b];
  int t = threadIdx.x;
  int lo = lb * SCAN_TILE + t * SCAN_ITEMS;
#pragma unroll
  for (int j = 0; j < SCAN_ITEMS; ++j) {
    int idx = lo + j;
    if (idx < len) {
      ptr[idx] += boff;
      if (isE) {
        int c = ecnt[idx];
        Binv[idx] = (c > 0) ? 1.0f / (float)c : 0.0f;
      }
    }
  }
  if (b == 0 && t == 0) { eptr[MM] = EE; nptr[NN] = EE; }
}

// ---------------- CSR fill: NO atomics (slots from rank_packed) -----------
__global__ __launch_bounds__(256) void fill_kernel(
    const int* __restrict__ node_idx, const int* __restrict__ edge_idx,
    const int* __restrict__ eptr, const int* __restrict__ nptr,
    const unsigned int* __restrict__ rank_packed,
    int* __restrict__ edge_nodes, int* __restrict__ node_edges) {
  int i = blockIdx.x * 256 + threadIdx.x;   // quad index
  if (i >= EE / 4) return;
  int4 nv = ((const int4*)node_idx)[i];
  int4 ev = ((const int4*)edge_idx)[i];
  uint4 rv = ((const uint4*)rank_packed)[i];
  int n[4] = {nv.x, nv.y, nv.z, nv.w};
  int e[4] = {ev.x, ev.y, ev.z, ev.w};
  unsigned int rp[4] = {rv.x, rv.y, rv.z, rv.w};
#pragma unroll
  for (int j = 0; j < 4; ++j) {
    edge_nodes[eptr[e[j]] + (int)(rp[j] & 0xFFFFu)] = n[j];
    node_edges[nptr[n[j]] + (int)(rp[j] >> 16)] = e[j];
  }
}

// ---------------- Dinv from node CSR (no atomics) -------------------------
__global__ __launch_bounds__(256) void dinv_csr_kernel(
    const int* __restrict__ nptr, const int* __restrict__ node_edges,
    const float* __restrict__ hw, float* __restrict__ Dinv) {
  int n = blockIdx.x * 256 + threadIdx.x;
  if (n >= NN) return;
  int lo = nptr[n], hi = nptr[n + 1];
  float d = 0.0f;
  for (int j = lo; j < hi; ++j) d += hw[node_edges[j]];
  Dinv[n] = (d > 0.0f) ? 1.0f / d : 0.0f;
}

// ---------------- fp32-compute GEMM: Y = X @ W (fp16 in/out) -------------
__device__ __forceinline__ void fma4(float4& acc, float s, const float4& m) {
  acc.x += s * m.x;
  acc.y += s * m.y;
  acc.z += s * m.z;
  acc.w += s * m.w;
}

__global__ __launch_bounds__(256) void gemm128_kernel(
    const __half* __restrict__ X, const float* __restrict__ W,
    __half* __restrict__ Y, int nrows) {
  __shared__ float Wl[128 * 128];
  float4* Wl4 = (float4*)Wl;
  const float4* W4 = (const float4*)W;
  for (int i = threadIdx.x; i < 128 * 32; i += 256) Wl4[i] = W4[i];
  __syncthreads();

  int tc = threadIdx.x & 15;   // 16 column threads
  int tr = threadIdx.x >> 4;   // 16 row threads
  int base = blockIdx.x * 64;
  int r[4];
  bool v[4];
#pragma unroll
  for (int j = 0; j < 4; ++j) {
    int rr = base + tr + j * 16;
    v[j] = rr < nrows;
    r[j] = v[j] ? rr : 0;
  }
  float4 acc[4][2];
#pragma unroll
  for (int j = 0; j < 4; ++j) {
    acc[j][0] = make_float4(0.f, 0.f, 0.f, 0.f);
    acc[j][1] = make_float4(0.f, 0.f, 0.f, 0.f);
  }
#pragma unroll 4
  for (int k4 = 0; k4 < 32; ++k4) {
    float4 xv[4];
#pragma unroll
    for (int j = 0; j < 4; ++j)
      xv[j] = h4_to_f4(((const half4*)X)[(size_t)r[j] * 32 + k4]);
#pragma unroll
    for (int kk = 0; kk < 4; ++kk) {
      float4 wva = Wl4[(k4 * 4 + kk) * 32 + tc];
      float4 wvb = Wl4[(k4 * 4 + kk) * 32 + 16 + tc];
#pragma unroll
      for (int j = 0; j < 4; ++j) {
        float xk = ((const float*)&xv[j])[kk];
        fma4(acc[j][0], xk, wva);
        fma4(acc[j][1], xk, wvb);
      }
    }
  }
#pragma unroll
  for (int j = 0; j < 4; ++j) {
    if (v[j]) {
      ((half4*)Y)[(size_t)r[j] * 32 + tc] = f4_to_h4(acc[j][0]);
      ((half4*)Y)[(size_t)r[j] * 32 + 16 + tc] = f4_to_h4(acc[j][1]);
    }
  }
}

// ---------------- edge aggregation: eraw[m] = Binv[m] * sum h[members] ---
__global__ __launch_bounds__(256) void edge_agg_kernel(
    const __half* __restrict__ hin, const int* __restrict__ eptr,
    const int* __restrict__ edge_nodes, const float* __restrict__ Binv,
    __half* __restrict__ eout) {
  int half_id = threadIdx.x >> 5;
  int lane = threadIdx.x & 31;
  int m = blockIdx.x * 8 + half_id;
  if (m >= MM) return;
  int lo = eptr[m], hi = eptr[m + 1];
  const half4* h4p = (const half4*)hin;
  float4 acc = make_float4(0.f, 0.f, 0.f, 0.f);
  int j = lo;
  for (; j + 4 <= hi; j += 4) {
    int n0 = edge_nodes[j + 0];
    int n1 = edge_nodes[j + 1];
    int n2 = edge_nodes[j + 2];
    int n3 = edge_nodes[j + 3];
    float4 a = h4_to_f4(h4p[(size_t)n0 * 32 + lane]);
    float4 b = h4_to_f4(h4p[(size_t)n1 * 32 + lane]);
    float4 c = h4_to_f4(h4p[(size_t)n2 * 32 + lane]);
    float4 d = h4_to_f4(h4p[(size_t)n3 * 32 + lane]);
    acc.x += (a.x + b.x) + (c.x + d.x);
    acc.y += (a.y + b.y) + (c.y + d.y);
    acc.z += (a.z + b.z) + (c.z + d.z);
    acc.w += (a.w + b.w) + (c.w + d.w);
  }
  for (; j < hi; ++j) {
    int n = edge_nodes[j];
    float4 a = h4_to_f4(h4p[(size_t)n * 32 + lane]);
    acc.x += a.x; acc.y += a.y; acc.z += a.z; acc.w += a.w;
  }
  float bi = Binv[m];
  acc.x *= bi; acc.y *= bi; acc.z *= bi; acc.w *= bi;
  ((half4*)eout)[(size_t)m * 32 + lane] = f4_to_h4(acc);
}

// ---------------- node aggregation + bias + relu, templated output -------
__device__ __forceinline__ void strow(float* Y, size_t i, float4 v) {
  ((float4*)Y)[i] = v;
}
__device__ __forceinline__ void strow(__half* Y, size_t i, float4 v) {
  ((half4*)Y)[i] = f4_to_h4(v);
}

template <typename TOUT>
__global__ __launch_bounds__(256) void node_agg_kernel(
    const __half* __restrict__ ein, const int* __restrict__ nptr,
    const int* __restrict__ node_edges, const float* __restrict__ Dinv,
    const float* __restrict__ bias, TOUT* __restrict__ out) {
  int half_id = threadIdx.x >> 5;
  int lane = threadIdx.x & 31;
  int n = blockIdx.x * 8 + half_id;
  if (n >= NN) return;
  int lo = nptr[n], hi = nptr[n + 1];
  const half4* e4 = (const half4*)ein;
  float4 acc = make_float4(0.f, 0.f, 0.f, 0.f);
  int j = lo;
  for (; j + 4 <= hi; j += 4) {
    int m0 = node_edges[j + 0];
    int m1 = node_edges[j + 1];
    int m2 = node_edges[j + 2];
    int m3 = node_edges[j + 3];
    float4 a = h4_to_f4(e4[(size_t)m0 * 32 + lane]);
    float4 b = h4_to_f4(e4[(size_t)m1 * 32 + lane]);
    float4 c = h4_to_f4(e4[(size_t)m2 * 32 + lane]);
    float4 d = h4_to_f4(e4[(size_t)m3 * 32 + lane]);
    acc.x += (a.x + b.x) + (c.x + d.x);
    acc.y += (a.y + b.y) + (c.y + d.y);
    acc.z += (a.z + b.z) + (c.z + d.z);
    acc.w += (a.w + b.w) + (c.w + d.w);
  }
  for (; j < hi; ++j) {
    int m = node_edges[j];
    float4 a = h4_to_f4(e4[(size_t)m * 32 + lane]);
    acc.x += a.x; acc.y += a.y; acc.z += a.z; acc.w += a.w;
  }
  float di = Dinv[n];
  float4 bb = ((const float4*)bias)[lane];
  float4 rv;
  rv.x = fmaxf(di * acc.x + bb.x, 0.f);
  rv.y = fmaxf(di * acc.y + bb.y, 0.f);
  rv.z = fmaxf(di * acc.z + bb.z, 0.f);
  rv.w = fmaxf(di * acc.w + bb.w, 0.f);
  strow(out, (size_t)n * 32 + lane, rv);
}

// ---------------- host-side launch ---------------------------------------
extern "C" void kernel_launch(void* const* d_in, const int* in_sizes, int n_in,
                              void* d_out, int out_size, void* d_ws, size_t ws_size,
                              hipStream_t stream) {
  const float* x = (const float*)d_in[0];
  const int* hidx = (const int*)d_in[1];
  const int* node_idx = hidx;        // hyperedge_index[0]
  const int* edge_idx = hidx + EE;   // hyperedge_index[1]
  const float* hw = (const float*)d_in[2];
  // d_in[3] = hyperedge_attr (unused), d_in[4] = batch (unused)
  const float* W1 = (const float*)d_in[5];
  const float* b1 = (const float*)d_in[6];
  const float* W2 = (const float*)d_in[7];
  const float* b2 = (const float*)d_in[8];
  const float* W3 = (const float*)d_in[9];
  const float* b3 = (const float*)d_in[10];
  float* out = (float*)d_out;

  char* ws = (char*)d_ws;
  size_t off = 0;
  auto alloc = [&](size_t bytes) -> char* {
    char* p = ws + off;
    off = align256(off + bytes);
    return p;
  };
  __half* xh   = (__half*)alloc(sizeof(__half) * (size_t)NN * 128);  // 25.6 MB
  __half* h    = (__half*)alloc(sizeof(__half) * (size_t)NN * 128);  // 25.6 MB
  __half* eraw = (__half*)alloc(sizeof(__half) * (size_t)MM * 128);  // 5.12 MB
  __half* et   = (__half*)alloc(sizeof(__half) * (size_t)MM * 128);  // 5.12 MB
  // contiguous zero region: [ecnt MM][ncnt NN]
  int*   zr    = (int*)alloc(sizeof(int) * (size_t)(MM + NN));
  int*   ecnt  = zr;
  int*   ncnt  = zr + MM;
  int*   eptr  = (int*)alloc(sizeof(int) * (MM + 1));
  int*   nptr  = (int*)alloc(sizeof(int) * (NN + 1));
  int*   bsum  = (int*)alloc(sizeof(int) * NB_TOT);
  float* Binv  = (float*)alloc(sizeof(float) * MM);
  float* Dinv  = (float*)alloc(sizeof(float) * NN);
  unsigned int* rank_packed = (unsigned int*)alloc(sizeof(int) * (size_t)EE);
  int* edge_nodes = (int*)alloc(sizeof(int) * (size_t)EE);           // 6.4 MB
  int* node_edges = (int*)alloc(sizeof(int) * (size_t)EE);           // 6.4 MB
  (void)ws_size; (void)in_sizes; (void)n_in; (void)out_size;

  // EE/4 = 400000 is NOT divisible by 256 -> round UP (guard in kernels).
  const int quad_grid = (EE / 4 + 255) / 256;

  // ---- graph precompute (once per call; indices are runtime inputs) ----
  zero_i32_kernel<<<256, 256, 0, stream>>>(zr, MM + NN);
  count_kernel<<<quad_grid, 256, 0, stream>>>(node_idx, edge_idx, ecnt, ncnt,
                                              rank_packed);
  scan_partial_kernel<<<NB_TOT, SCAN_BLOCK, 0, stream>>>(ecnt, ncnt, eptr, nptr, bsum);
  scan_bsum_kernel<<<1, 64, 0, stream>>>(bsum);
  scan_fixup_kernel<<<NB_TOT, SCAN_BLOCK, 0, stream>>>(eptr, nptr, ecnt, bsum, Binv);
  fill_kernel<<<quad_grid, 256, 0, stream>>>(node_idx, edge_idx, eptr, nptr,
                                             rank_packed, edge_nodes, node_edges);
  dinv_csr_kernel<<<(NN + 255) / 256, 256, 0, stream>>>(nptr, node_edges, hw, Dinv);
  cvt_f2h_kernel<<<1024, 256, 0, stream>>>(x, xh, NN * 32);

  const int gemmE_grid = (MM + 63) / 64;   // GEMM now runs on 20k edge rows
  const int eagg_grid = MM / 8;    // 20000 % 8 == 0
  const int nagg_grid = NN / 8;    // 100000 % 8 == 0

  // ---- layer 1: eagg(xh) -> gemm(W1) -> nagg(+b1, relu) ----
  edge_agg_kernel<<<eagg_grid, 256, 0, stream>>>(xh, eptr, edge_nodes, Binv, eraw);
  gemm128_kernel<<<gemmE_grid, 256, 0, stream>>>(eraw, W1, et, MM);
  node_agg_kernel<__half><<<nagg_grid, 256, 0, stream>>>(et, nptr, node_edges,
                                                         Dinv, b1, h);
  // ---- layer 2 (reuse xh as the second ping-pong buffer) ----
  edge_agg_kernel<<<eagg_grid, 256, 0, stream>>>(h, eptr, edge_nodes, Binv, eraw);
  gemm128_kernel<<<gemmE_grid, 256, 0, stream>>>(eraw, W2, et, MM);
  node_agg_kernel<__half><<<nagg_grid, 256, 0, stream>>>(et, nptr, node_edges,
                                                         Dinv, b2, xh);
  // ---- layer 3 ----
  edge_agg_kernel<<<eagg_grid, 256, 0, stream>>>(xh, eptr, edge_nodes, Binv, eraw);
  gemm128_kernel<<<gemmE_grid, 256, 0, stream>>>(eraw, W3, et, MM);
  node_agg_kernel<float><<<nagg_grid, 256, 0, stream>>>(et, nptr, node_edges,
                                                        Dinv, b3, out);
}

// Round 8
// 628.862 us; speedup vs baseline: 2.2441x; 1.0009x over previous
//
#include <hip/hip_runtime.h>
#include <hip/hip_fp16.h>

#define NN 100000
#define MM 20000
#define EE 1600000
// C = 128 channels. fp16 intermediates: row = 128 half = 256 B = 32x half4.
// Weight multiply DEFERRED to hyperedge side (20k rows):
//   X' = D^-1 H B^-1 H^T X Theta  ==  D^-1 H ( (B^-1 H^T X) Theta )
// CSR build: LDS-privatized histograms, ZERO global atomics.

#define NBLK_E 256
#define CHUNK_E (EE / NBLK_E)      // 6250
#define NBLK_N 128
#define CHUNK_N (EE / NBLK_N)      // 12500
#define NRANGE 25000               // nodes per LDS pass (100 KB)

#define SCAN_BLOCK 256
#define SCAN_ITEMS 8
#define SCAN_TILE (SCAN_BLOCK * SCAN_ITEMS)          // 2048
#define NB_E ((MM + SCAN_TILE - 1) / SCAN_TILE)      // 10
#define NB_N ((NN + SCAN_TILE - 1) / SCAN_TILE)      // 49
#define NB_TOT (NB_E + NB_N)                         // 59

static inline size_t align256(size_t x) { return (x + 255) & ~(size_t)255; }

struct alignas(8) half4 { __half2 lo, hi; };

__device__ __forceinline__ float4 h4_to_f4(half4 v) {
  float2 a = __half22float2(v.lo);
  float2 b = __half22float2(v.hi);
  return make_float4(a.x, a.y, b.x, b.y);
}
__device__ __forceinline__ half4 f4_to_h4(float4 v) {
  half4 r;
  r.lo = __float22half2_rn(make_float2(v.x, v.y));
  r.hi = __float22half2_rn(make_float2(v.z, v.w));
  return r;
}

// ---------------- fp32 -> fp16 convert (x, once) --------------------------
__global__ __launch_bounds__(256) void cvt_f2h_kernel(
    const float* __restrict__ in, __half* __restrict__ out, int n4) {
  int i = blockIdx.x * 256 + threadIdx.x;
  int stride = gridDim.x * 256;
  for (; i < n4; i += stride) {
    float4 v = ((const float4*)in)[i];
    ((half4*)out)[i] = f4_to_h4(v);
  }
}

// ---------------- per-block edge histogram in LDS (NO global atomics) ----
// Block b owns incidences [b*CHUNK_E, (b+1)*CHUNK_E). LDS atomicAdd returns
// the local rank; block dumps its histogram row to bcnt_e[b][MM].
__global__ __launch_bounds__(256) void ehist_kernel(
    const int* __restrict__ edge_idx,
    int* __restrict__ bcnt_e, unsigned short* __restrict__ lrank_e) {
  extern __shared__ int hist[];   // MM ints = 80 KB
  int b = blockIdx.x;
  for (int k = threadIdx.x; k < MM; k += 256) hist[k] = 0;
  __syncthreads();
  int lo = b * CHUNK_E, hi = lo + CHUNK_E;
  for (int i = lo + threadIdx.x; i < hi; i += 256) {
    int e = edge_idx[i];
    int r = atomicAdd(&hist[e], 1);      // LDS atomic
    lrank_e[i] = (unsigned short)r;      // coalesced 2B store
  }
  __syncthreads();
  int* row = bcnt_e + (size_t)b * MM;
  for (int k = threadIdx.x; k < MM; k += 256) row[k] = hist[k];
}

// ---------------- per-block node histogram: 4 LDS passes of 25000 --------
__global__ __launch_bounds__(256) void nhist_kernel(
    const int* __restrict__ node_idx,
    int* __restrict__ bcnt_n, unsigned short* __restrict__ lrank_n) {
  extern __shared__ int hist[];   // NRANGE ints = 100 KB
  int b = blockIdx.x;
  int lo = b * CHUNK_N, hi = lo + CHUNK_N;
  int* row = bcnt_n + (size_t)b * NN;
  for (int p = 0; p < 4; ++p) {
    int base = p * NRANGE;
    for (int k = threadIdx.x; k < NRANGE; k += 256) hist[k] = 0;
    __syncthreads();
    for (int i = lo + threadIdx.x; i < hi; i += 256) {
      int n = node_idx[i] - base;
      if ((unsigned)n < (unsigned)NRANGE) {
        int r = atomicAdd(&hist[n], 1);  // LDS atomic
        lrank_n[i] = (unsigned short)r;
      }
    }
    __syncthreads();
    for (int k = threadIdx.x; k < NRANGE; k += 256) row[base + k] = hist[k];
    __syncthreads();
  }
}

// ---------------- column scans: per-bucket exclusive prefix over blocks --
__global__ __launch_bounds__(256) void colscan_e_kernel(
    int* __restrict__ bcnt_e, int* __restrict__ ecnt) {
  int e = blockIdx.x * 256 + threadIdx.x;
  if (e >= MM) return;
  int run = 0;
#pragma unroll 8
  for (int b = 0; b < NBLK_E; ++b) {
    size_t idx = (size_t)b * MM + e;
    int v = bcnt_e[idx];
    bcnt_e[idx] = run;
    run += v;
  }
  ecnt[e] = run;
}

__global__ __launch_bounds__(256) void colscan_n_kernel(
    int* __restrict__ bcnt_n, int* __restrict__ ncnt) {
  int n = blockIdx.x * 256 + threadIdx.x;
  if (n >= NN) return;
  int run = 0;
#pragma unroll 8
  for (int b = 0; b < NBLK_N; ++b) {
    size_t idx = (size_t)b * NN + n;
    int v = bcnt_n[idx];
    bcnt_n[idx] = run;
    run += v;
  }
  ncnt[n] = run;
}

// ---------------- hierarchical scan (both arrays in one 3-dispatch pass) --
__global__ __launch_bounds__(SCAN_BLOCK) void scan_partial_kernel(
    const int* __restrict__ ecnt, const int* __restrict__ ncnt,
    int* __restrict__ eptr, int* __restrict__ nptr, int* __restrict__ bsum) {
  __shared__ int lds[SCAN_BLOCK];
  int b = blockIdx.x;
  const int* cnt; int* ptr; int len; int lb;
  if (b < NB_E) { cnt = ecnt; ptr = eptr; len = MM; lb = b; }
  else          { cnt = ncnt; ptr = nptr; len = NN; lb = b - NB_E; }
  int t = threadIdx.x;
  int lo = lb * SCAN_TILE + t * SCAN_ITEMS;
  int v[SCAN_ITEMS];
  int s = 0;
#pragma unroll
  for (int j = 0; j < SCAN_ITEMS; ++j) {
    int idx = lo + j;
    v[j] = (idx < len) ? cnt[idx] : 0;
    s += v[j];
  }
  lds[t] = s;
  __syncthreads();
  for (int d = 1; d < SCAN_BLOCK; d <<= 1) {
    int o = (t >= d) ? lds[t - d] : 0;
    __syncthreads();
    lds[t] += o;
    __syncthreads();
  }
  int run = lds[t] - s;
#pragma unroll
  for (int j = 0; j < SCAN_ITEMS; ++j) {
    int idx = lo + j;
    if (idx < len) ptr[idx] = run;
    run += v[j];
  }
  if (t == SCAN_BLOCK - 1) bsum[b] = lds[t];
}

__global__ void scan_bsum_kernel(int* __restrict__ bsum) {
  int t = threadIdx.x;
  if (t == 0) {
    int run = 0;
    for (int i = 0; i < NB_E; ++i) { int c = bsum[i]; bsum[i] = run; run += c; }
  } else if (t == 1) {
    int run = 0;
    for (int i = NB_E; i < NB_TOT; ++i) { int c = bsum[i]; bsum[i] = run; run += c; }
  }
}

__global__ __launch_bounds__(SCAN_BLOCK) void scan_fixup_kernel(
    int* __restrict__ eptr, int* __restrict__ nptr,
    const int* __restrict__ ecnt, const int* __restrict__ bsum,
    float* __restrict__ Binv) {
  int b = blockIdx.x;
  int* ptr; int len; int lb; bool isE;
  if (b < NB_E) { ptr = eptr; len = MM; lb = b; isE = true; }
  else          { ptr = nptr; len = NN; lb = b - NB_E; isE = false; }
  int boff = bsum[b];
  int t = threadIdx.x;
  int lo = lb * SCAN_TILE + t * SCAN_ITEMS;
#pragma unroll
  for (int j = 0; j < SCAN_ITEMS; ++j) {
    int idx = lo + j;
    if (idx < len) {
      ptr[idx] += boff;
      if (isE) {
        int c = ecnt[idx];
        Binv[idx] = (c > 0) ? 1.0f / (float)c : 0.0f;
      }
    }
  }
  if (b == 0 && t == 0) { eptr[MM] = EE; nptr[NN] = EE; }
}

// ---------------- CSR fill v2: slot = ptr + block-base + local rank ------
__global__ __launch_bounds__(256) void fill2_kernel(
    const int* __restrict__ node_idx, const int* __restrict__ edge_idx,
    const int* __restrict__ eptr, const int* __restrict__ nptr,
    const int* __restrict__ bcnt_e, const int* __restrict__ bcnt_n,
    const unsigned short* __restrict__ lrank_e,
    const unsigned short* __restrict__ lrank_n,
    int* __restrict__ edge_nodes, int* __restrict__ node_edges) {
  int i = blockIdx.x * 256 + threadIdx.x;
  if (i >= EE) return;
  int e = edge_idx[i];
  int n = node_idx[i];
  int be = i / CHUNK_E;
  int bn = i / CHUNK_N;
  int slotE = eptr[e] + bcnt_e[(size_t)be * MM + e] + (int)lrank_e[i];
  edge_nodes[slotE] = n;
  int slotN = nptr[n] + bcnt_n[(size_t)bn * NN + n] + (int)lrank_n[i];
  node_edges[slotN] = e;
}

// ---------------- Dinv from node CSR -------------------------------------
__global__ __launch_bounds__(256) void dinv_csr_kernel(
    const int* __restrict__ nptr, const int* __restrict__ node_edges,
    const float* __restrict__ hw, float* __restrict__ Dinv) {
  int n = blockIdx.x * 256 + threadIdx.x;
  if (n >= NN) return;
  int lo = nptr[n], hi = nptr[n + 1];
  float d = 0.0f;
  for (int j = lo; j < hi; ++j) d += hw[node_edges[j]];
  Dinv[n] = (d > 0.0f) ? 1.0f / d : 0.0f;
}

// ---------------- fp32-compute GEMM: Y = X @ W (fp16 in/out) -------------
__device__ __forceinline__ void fma4(float4& acc, float s, const float4& m) {
  acc.x += s * m.x;
  acc.y += s * m.y;
  acc.z += s * m.z;
  acc.w += s * m.w;
}

__global__ __launch_bounds__(256) void gemm128_kernel(
    const __half* __restrict__ X, const float* __restrict__ W,
    __half* __restrict__ Y, int nrows) {
  __shared__ float Wl[128 * 128];
  float4* Wl4 = (float4*)Wl;
  const float4* W4 = (const float4*)W;
  for (int i = threadIdx.x; i < 128 * 32; i += 256) Wl4[i] = W4[i];
  __syncthreads();

  int tc = threadIdx.x & 15;
  int tr = threadIdx.x >> 4;
  int base = blockIdx.x * 64;
  int r[4];
  bool v[4];
#pragma unroll
  for (int j = 0; j < 4; ++j) {
    int rr = base + tr + j * 16;
    v[j] = rr < nrows;
    r[j] = v[j] ? rr : 0;
  }
  float4 acc[4][2];
#pragma unroll
  for (int j = 0; j < 4; ++j) {
    acc[j][0] = make_float4(0.f, 0.f, 0.f, 0.f);
    acc[j][1] = make_float4(0.f, 0.f, 0.f, 0.f);
  }
#pragma unroll 4
  for (int k4 = 0; k4 < 32; ++k4) {
    float4 xv[4];
#pragma unroll
    for (int j = 0; j < 4; ++j)
      xv[j] = h4_to_f4(((const half4*)X)[(size_t)r[j] * 32 + k4]);
#pragma unroll
    for (int kk = 0; kk < 4; ++kk) {
      float4 wva = Wl4[(k4 * 4 + kk) * 32 + tc];
      float4 wvb = Wl4[(k4 * 4 + kk) * 32 + 16 + tc];
#pragma unroll
      for (int j = 0; j < 4; ++j) {
        float xk = ((const float*)&xv[j])[kk];
        fma4(acc[j][0], xk, wva);
        fma4(acc[j][1], xk, wvb);
      }
    }
  }
#pragma unroll
  for (int j = 0; j < 4; ++j) {
    if (v[j]) {
      ((half4*)Y)[(size_t)r[j] * 32 + tc] = f4_to_h4(acc[j][0]);
      ((half4*)Y)[(size_t)r[j] * 32 + 16 + tc] = f4_to_h4(acc[j][1]);
    }
  }
}

// ---------------- edge aggregation: eraw[m] = Binv[m] * sum h[members] ---
__global__ __launch_bounds__(256) void edge_agg_kernel(
    const __half* __restrict__ hin, const int* __restrict__ eptr,
    const int* __restrict__ edge_nodes, const float* __restrict__ Binv,
    __half* __restrict__ eout) {
  int half_id = threadIdx.x >> 5;
  int lane = threadIdx.x & 31;
  int m = blockIdx.x * 8 + half_id;
  if (m >= MM) return;
  int lo = eptr[m], hi = eptr[m + 1];
  const half4* h4p = (const half4*)hin;
  float4 acc = make_float4(0.f, 0.f, 0.f, 0.f);
  int j = lo;
  for (; j + 4 <= hi; j += 4) {
    int n0 = edge_nodes[j + 0];
    int n1 = edge_nodes[j + 1];
    int n2 = edge_nodes[j + 2];
    int n3 = edge_nodes[j + 3];
    float4 a = h4_to_f4(h4p[(size_t)n0 * 32 + lane]);
    float4 b = h4_to_f4(h4p[(size_t)n1 * 32 + lane]);
    float4 c = h4_to_f4(h4p[(size_t)n2 * 32 + lane]);
    float4 d = h4_to_f4(h4p[(size_t)n3 * 32 + lane]);
    acc.x += (a.x + b.x) + (c.x + d.x);
    acc.y += (a.y + b.y) + (c.y + d.y);
    acc.z += (a.z + b.z) + (c.z + d.z);
    acc.w += (a.w + b.w) + (c.w + d.w);
  }
  for (; j < hi; ++j) {
    int n = edge_nodes[j];
    float4 a = h4_to_f4(h4p[(size_t)n * 32 + lane]);
    acc.x += a.x; acc.y += a.y; acc.z += a.z; acc.w += a.w;
  }
  float bi = Binv[m];
  acc.x *= bi; acc.y *= bi; acc.z *= bi; acc.w *= bi;
  ((half4*)eout)[(size_t)m * 32 + lane] = f4_to_h4(acc);
}

// ---------------- node aggregation + bias + relu, templated output -------
__device__ __forceinline__ void strow(float* Y, size_t i, float4 v) {
  ((float4*)Y)[i] = v;
}
__device__ __forceinline__ void strow(__half* Y, size_t i, float4 v) {
  ((half4*)Y)[i] = f4_to_h4(v);
}

template <typename TOUT>
__global__ __launch_bounds__(256) void node_agg_kernel(
    const __half* __restrict__ ein, const int* __restrict__ nptr,
    const int* __restrict__ node_edges, const float* __restrict__ Dinv,
    const float* __restrict__ bias, TOUT* __restrict__ out) {
  int half_id = threadIdx.x >> 5;
  int lane = threadIdx.x & 31;
  int n = blockIdx.x * 8 + half_id;
  if (n >= NN) return;
  int lo = nptr[n], hi = nptr[n + 1];
  const half4* e4 = (const half4*)ein;
  float4 acc = make_float4(0.f, 0.f, 0.f, 0.f);
  int j = lo;
  for (; j + 4 <= hi; j += 4) {
    int m0 = node_edges[j + 0];
    int m1 = node_edges[j + 1];
    int m2 = node_edges[j + 2];
    int m3 = node_edges[j + 3];
    float4 a = h4_to_f4(e4[(size_t)m0 * 32 + lane]);
    float4 b = h4_to_f4(e4[(size_t)m1 * 32 + lane]);
    float4 c = h4_to_f4(e4[(size_t)m2 * 32 + lane]);
    float4 d = h4_to_f4(e4[(size_t)m3 * 32 + lane]);
    acc.x += (a.x + b.x) + (c.x + d.x);
    acc.y += (a.y + b.y) + (c.y + d.y);
    acc.z += (a.z + b.z) + (c.z + d.z);
    acc.w += (a.w + b.w) + (c.w + d.w);
  }
  for (; j < hi; ++j) {
    int m = node_edges[j];
    float4 a = h4_to_f4(e4[(size_t)m * 32 + lane]);
    acc.x += a.x; acc.y += a.y; acc.z += a.z; acc.w += a.w;
  }
  float di = Dinv[n];
  float4 bb = ((const float4*)bias)[lane];
  float4 rv;
  rv.x = fmaxf(di * acc.x + bb.x, 0.f);
  rv.y = fmaxf(di * acc.y + bb.y, 0.f);
  rv.z = fmaxf(di * acc.z + bb.z, 0.f);
  rv.w = fmaxf(di * acc.w + bb.w, 0.f);
  strow(out, (size_t)n * 32 + lane, rv);
}

// ---------------- host-side launch ---------------------------------------
extern "C" void kernel_launch(void* const* d_in, const int* in_sizes, int n_in,
                              void* d_out, int out_size, void* d_ws, size_t ws_size,
                              hipStream_t stream) {
  const float* x = (const float*)d_in[0];
  const int* hidx = (const int*)d_in[1];
  const int* node_idx = hidx;        // hyperedge_index[0]
  const int* edge_idx = hidx + EE;   // hyperedge_index[1]
  const float* hw = (const float*)d_in[2];
  // d_in[3] = hyperedge_attr (unused), d_in[4] = batch (unused)
  const float* W1 = (const float*)d_in[5];
  const float* b1 = (const float*)d_in[6];
  const float* W2 = (const float*)d_in[7];
  const float* b2 = (const float*)d_in[8];
  const float* W3 = (const float*)d_in[9];
  const float* b3 = (const float*)d_in[10];
  float* out = (float*)d_out;

  char* ws = (char*)d_ws;
  size_t off = 0;
  auto alloc = [&](size_t bytes) -> char* {
    char* p = ws + off;
    off = align256(off + bytes);
    return p;
  };
  __half* xh   = (__half*)alloc(sizeof(__half) * (size_t)NN * 128);  // 25.6 MB
  __half* h    = (__half*)alloc(sizeof(__half) * (size_t)NN * 128);  // 25.6 MB
  __half* eraw = (__half*)alloc(sizeof(__half) * (size_t)MM * 128);  // 5.12 MB
  __half* et   = (__half*)alloc(sizeof(__half) * (size_t)MM * 128);  // 5.12 MB
  int*   bcnt_e = (int*)alloc(sizeof(int) * (size_t)NBLK_E * MM);    // 20.5 MB
  int*   bcnt_n = (int*)alloc(sizeof(int) * (size_t)NBLK_N * NN);    // 51.2 MB
  unsigned short* lrank_e = (unsigned short*)alloc(sizeof(short) * (size_t)EE);
  unsigned short* lrank_n = (unsigned short*)alloc(sizeof(short) * (size_t)EE);
  int*   ecnt  = (int*)alloc(sizeof(int) * MM);
  int*   ncnt  = (int*)alloc(sizeof(int) * NN);
  int*   eptr  = (int*)alloc(sizeof(int) * (MM + 1));
  int*   nptr  = (int*)alloc(sizeof(int) * (NN + 1));
  int*   bsum  = (int*)alloc(sizeof(int) * NB_TOT);
  float* Binv  = (float*)alloc(sizeof(float) * MM);
  float* Dinv  = (float*)alloc(sizeof(float) * NN);
  int* edge_nodes = (int*)alloc(sizeof(int) * (size_t)EE);           // 6.4 MB
  int* node_edges = (int*)alloc(sizeof(int) * (size_t)EE);           // 6.4 MB
  (void)ws_size; (void)in_sizes; (void)n_in; (void)out_size;

  // ---- graph precompute: no global atomics anywhere --------------------
  ehist_kernel<<<NBLK_E, 256, MM * sizeof(int), stream>>>(edge_idx, bcnt_e, lrank_e);
  nhist_kernel<<<NBLK_N, 256, NRANGE * sizeof(int), stream>>>(node_idx, bcnt_n, lrank_n);
  colscan_e_kernel<<<(MM + 255) / 256, 256, 0, stream>>>(bcnt_e, ecnt);
  colscan_n_kernel<<<(NN + 255) / 256, 256, 0, stream>>>(bcnt_n, ncnt);
  scan_partial_kernel<<<NB_TOT, SCAN_BLOCK, 0, stream>>>(ecnt, ncnt, eptr, nptr, bsum);
  scan_bsum_kernel<<<1, 64, 0, stream>>>(bsum);
  scan_fixup_kernel<<<NB_TOT, SCAN_BLOCK, 0, stream>>>(eptr, nptr, ecnt, bsum, Binv);
  fill2_kernel<<<(EE + 255) / 256, 256, 0, stream>>>(node_idx, edge_idx, eptr, nptr,
                                                     bcnt_e, bcnt_n, lrank_e, lrank_n,
                                                     edge_nodes, node_edges);
  dinv_csr_kernel<<<(NN + 255) / 256, 256, 0, stream>>>(nptr, node_edges, hw, Dinv);
  cvt_f2h_kernel<<<1024, 256, 0, stream>>>(x, xh, NN * 32);

  const int gemmE_grid = (MM + 63) / 64;
  const int eagg_grid = MM / 8;    // 20000 % 8 == 0
  const int nagg_grid = NN / 8;    // 100000 % 8 == 0

  // ---- layer 1: eagg(xh) -> gemm(W1) -> nagg(+b1, relu) ----
  edge_agg_kernel<<<eagg_grid, 256, 0, stream>>>(xh, eptr, edge_nodes, Binv, eraw);
  gemm128_kernel<<<gemmE_grid, 256, 0, stream>>>(eraw, W1, et, MM);
  node_agg_kernel<__half><<<nagg_grid, 256, 0, stream>>>(et, nptr, node_edges,
                                                         Dinv, b1, h);
  // ---- layer 2 (reuse xh as the second ping-pong buffer) ----
  edge_agg_kernel<<<eagg_grid, 256, 0, stream>>>(h, eptr, edge_nodes, Binv, eraw);
  gemm128_kernel<<<gemmE_grid, 256, 0, stream>>>(eraw, W2, et, MM);
  node_agg_kernel<__half><<<nagg_grid, 256, 0, stream>>>(et, nptr, node_edges,
                                                         Dinv, b2, xh);
  // ---- layer 3 ----
  edge_agg_kernel<<<eagg_grid, 256, 0, stream>>>(xh, eptr, edge_nodes, Binv, eraw);
  gemm128_kernel<<<gemmE_grid, 256, 0, stream>>>(eraw, W3, et, MM);
  node_agg_kernel<float><<<nagg_grid, 256, 0, stream>>>(et, nptr, node_edges,
                                                        Dinv, b3, out);
}

// Round 9
// 600.314 us; speedup vs baseline: 2.3508x; 1.0476x over previous
//
#include <hip/hip_runtime.h>
#include <hip/hip_fp16.h>

#define NN 100000
#define MM 20000
#define EE 1600000
// C = 128 channels. fp16 intermediates: row = 128 half = 256 B = 32x half4.
// Weight multiply DEFERRED to hyperedge side (20k rows).
// CSR build: LDS-privatized histograms, ZERO global atomics, u16 bcnt.

#define NBLK_E 256
#define CHUNK_E (EE / NBLK_E)      // 6250
#define NBLK_N 128
#define CHUNK_N (EE / NBLK_N)      // 12500
#define NRANGE2 50000              // nodes per paired-u16 pass (25000 words = 100 KB)

#define SCAN_BLOCK 256
#define SCAN_ITEMS 8
#define SCAN_TILE (SCAN_BLOCK * SCAN_ITEMS)          // 2048
#define NB_E ((MM + SCAN_TILE - 1) / SCAN_TILE)      // 10
#define NB_N ((NN + SCAN_TILE - 1) / SCAN_TILE)      // 49
#define NB_TOT (NB_E + NB_N)                         // 59

static inline size_t align256(size_t x) { return (x + 255) & ~(size_t)255; }

struct alignas(8) half4 { __half2 lo, hi; };

__device__ __forceinline__ float4 h4_to_f4(half4 v) {
  float2 a = __half22float2(v.lo);
  float2 b = __half22float2(v.hi);
  return make_float4(a.x, a.y, b.x, b.y);
}
__device__ __forceinline__ half4 f4_to_h4(float4 v) {
  half4 r;
  r.lo = __float22half2_rn(make_float2(v.x, v.y));
  r.hi = __float22half2_rn(make_float2(v.z, v.w));
  return r;
}

// ---------------- fp32 -> fp16 convert (x, once) --------------------------
__global__ __launch_bounds__(256) void cvt_f2h_kernel(
    const float* __restrict__ in, __half* __restrict__ out, int n4) {
  int i = blockIdx.x * 256 + threadIdx.x;
  int stride = gridDim.x * 256;
  for (; i < n4; i += stride) {
    float4 v = ((const float4*)in)[i];
    ((half4*)out)[i] = f4_to_h4(v);
  }
}

// ---------------- per-block edge histogram in LDS ------------------------
__global__ __launch_bounds__(256) void ehist_kernel(
    const int* __restrict__ edge_idx,
    unsigned short* __restrict__ bcnt_e, unsigned short* __restrict__ lrank_e) {
  extern __shared__ int hist[];   // MM ints = 80 KB
  int b = blockIdx.x;
  for (int k = threadIdx.x; k < MM; k += 256) hist[k] = 0;
  __syncthreads();
  int lo = b * CHUNK_E, hi = lo + CHUNK_E;
  for (int i = lo + threadIdx.x; i < hi; i += 256) {
    int e = edge_idx[i];
    int r = atomicAdd(&hist[e], 1);      // LDS atomic
    lrank_e[i] = (unsigned short)r;
  }
  __syncthreads();
  unsigned short* row = bcnt_e + (size_t)b * MM;
  for (int k = threadIdx.x; k < MM / 2; k += 256) {
    ushort2 w;
    w.x = (unsigned short)hist[2 * k];
    w.y = (unsigned short)hist[2 * k + 1];
    ((ushort2*)row)[k] = w;
  }
}

// ---------------- per-block node histogram: paired-u16, 2 passes ---------
// Two nodes share one 32-bit LDS word; atomicAdd(1) / atomicAdd(1<<16).
// Low field <= CHUNK_N=12500 < 2^14 so it never carries into the high field.
__global__ __launch_bounds__(256) void nhist_kernel(
    const int* __restrict__ node_idx,
    unsigned short* __restrict__ bcnt_n, unsigned short* __restrict__ lrank_n) {
  extern __shared__ unsigned int histp[];   // NRANGE2/2 = 25000 words = 100 KB
  int b = blockIdx.x;
  int lo = b * CHUNK_N, hi = lo + CHUNK_N;
  unsigned short* row = bcnt_n + (size_t)b * NN;
  for (int p = 0; p < 2; ++p) {
    int base = p * NRANGE2;
    for (int k = threadIdx.x; k < NRANGE2 / 2; k += 256) histp[k] = 0;
    __syncthreads();
    for (int i = lo + threadIdx.x; i < hi; i += 256) {
      int n = node_idx[i] - base;
      if ((unsigned)n < (unsigned)NRANGE2) {
        unsigned add = (n & 1) ? 0x10000u : 1u;
        unsigned old = atomicAdd(&histp[n >> 1], add);
        lrank_n[i] = (unsigned short)((old >> ((n & 1) * 16)) & 0xFFFFu);
      }
    }
    __syncthreads();
    for (int k = threadIdx.x; k < NRANGE2 / 2; k += 256) {
      unsigned w = histp[k];
      ushort2 o;
      o.x = (unsigned short)(w & 0xFFFFu);
      o.y = (unsigned short)(w >> 16);
      ((ushort2*)(row + base))[k] = o;
    }
    __syncthreads();
  }
}

// ---------------- merged column scans (edge cols + node cols) ------------
__global__ __launch_bounds__(256) void colscan_kernel(
    unsigned short* __restrict__ bcnt_e, unsigned short* __restrict__ bcnt_n,
    int* __restrict__ ecnt, int* __restrict__ ncnt) {
  int i = blockIdx.x * 256 + threadIdx.x;
  if (i < MM) {
    int run = 0;
#pragma unroll 8
    for (int b = 0; b < NBLK_E; ++b) {
      size_t idx = (size_t)b * MM + i;
      int v = bcnt_e[idx];
      bcnt_e[idx] = (unsigned short)run;
      run += v;
    }
    ecnt[i] = run;
  } else if (i < MM + NN) {
    int n = i - MM;
    int run = 0;
#pragma unroll 8
    for (int b = 0; b < NBLK_N; ++b) {
      size_t idx = (size_t)b * NN + n;
      int v = bcnt_n[idx];
      bcnt_n[idx] = (unsigned short)run;
      run += v;
    }
    ncnt[n] = run;
  }
}

// ---------------- hierarchical scan (both arrays, 3 dispatches) ----------
__global__ __launch_bounds__(SCAN_BLOCK) void scan_partial_kernel(
    const int* __restrict__ ecnt, const int* __restrict__ ncnt,
    int* __restrict__ eptr, int* __restrict__ nptr, int* __restrict__ bsum) {
  __shared__ int lds[SCAN_BLOCK];
  int b = blockIdx.x;
  const int* cnt; int* ptr; int len; int lb;
  if (b < NB_E) { cnt = ecnt; ptr = eptr; len = MM; lb = b; }
  else          { cnt = ncnt; ptr = nptr; len = NN; lb = b - NB_E; }
  int t = threadIdx.x;
  int lo = lb * SCAN_TILE + t * SCAN_ITEMS;
  int v[SCAN_ITEMS];
  int s = 0;
#pragma unroll
  for (int j = 0; j < SCAN_ITEMS; ++j) {
    int idx = lo + j;
    v[j] = (idx < len) ? cnt[idx] : 0;
    s += v[j];
  }
  lds[t] = s;
  __syncthreads();
  for (int d = 1; d < SCAN_BLOCK; d <<= 1) {
    int o = (t >= d) ? lds[t - d] : 0;
    __syncthreads();
    lds[t] += o;
    __syncthreads();
  }
  int run = lds[t] - s;
#pragma unroll
  for (int j = 0; j < SCAN_ITEMS; ++j) {
    int idx = lo + j;
    if (idx < len) ptr[idx] = run;
    run += v[j];
  }
  if (t == SCAN_BLOCK - 1) bsum[b] = lds[t];
}

__global__ void scan_bsum_kernel(int* __restrict__ bsum) {
  int t = threadIdx.x;
  if (t == 0) {
    int run = 0;
    for (int i = 0; i < NB_E; ++i) { int c = bsum[i]; bsum[i] = run; run += c; }
  } else if (t == 1) {
    int run = 0;
    for (int i = NB_E; i < NB_TOT; ++i) { int c = bsum[i]; bsum[i] = run; run += c; }
  }
}

__global__ __launch_bounds__(SCAN_BLOCK) void scan_fixup_kernel(
    int* __restrict__ eptr, int* __restrict__ nptr,
    const int* __restrict__ ecnt, const int* __restrict__ bsum,
    float* __restrict__ Binv) {
  int b = blockIdx.x;
  int* ptr; int len; int lb; bool isE;
  if (b < NB_E) { ptr = eptr; len = MM; lb = b; isE = true; }
  else          { ptr = nptr; len = NN; lb = b - NB_E; isE = false; }
  int boff = bsum[b];
  int t = threadIdx.x;
  int lo = lb * SCAN_TILE + t * SCAN_ITEMS;
#pragma unroll
  for (int j = 0; j < SCAN_ITEMS; ++j) {
    int idx = lo + j;
    if (idx < len) {
      ptr[idx] += boff;
      if (isE) {
        int c = ecnt[idx];
        Binv[idx] = (c > 0) ? 1.0f / (float)c : 0.0f;
      }
    }
  }
  if (b == 0 && t == 0) { eptr[MM] = EE; nptr[NN] = EE; }
}

// ---------------- CSR fill: slot = ptr + block-base + local rank ---------
__global__ __launch_bounds__(256) void fill2_kernel(
    const int* __restrict__ node_idx, const int* __restrict__ edge_idx,
    const int* __restrict__ eptr, const int* __restrict__ nptr,
    const unsigned short* __restrict__ bcnt_e,
    const unsigned short* __restrict__ bcnt_n,
    const unsigned short* __restrict__ lrank_e,
    const unsigned short* __restrict__ lrank_n,
    int* __restrict__ edge_nodes, int* __restrict__ node_edges) {
  int i = blockIdx.x * 256 + threadIdx.x;
  if (i >= EE) return;
  int e = edge_idx[i];
  int n = node_idx[i];
  int be = i / CHUNK_E;
  int bn = i / CHUNK_N;
  int slotE = eptr[e] + (int)bcnt_e[(size_t)be * MM + e] + (int)lrank_e[i];
  edge_nodes[slotE] = n;
  int slotN = nptr[n] + (int)bcnt_n[(size_t)bn * NN + n] + (int)lrank_n[i];
  node_edges[slotN] = e;
}

// ---------------- Dinv from node CSR -------------------------------------
__global__ __launch_bounds__(256) void dinv_csr_kernel(
    const int* __restrict__ nptr, const int* __restrict__ node_edges,
    const float* __restrict__ hw, float* __restrict__ Dinv) {
  int n = blockIdx.x * 256 + threadIdx.x;
  if (n >= NN) return;
  int lo = nptr[n], hi = nptr[n + 1];
  float d = 0.0f;
  for (int j = lo; j < hi; ++j) d += hw[node_edges[j]];
  Dinv[n] = (d > 0.0f) ? 1.0f / d : 0.0f;
}

// ---------------- fp32-compute GEMM: Y = X @ W (fp16 in/out) -------------
__device__ __forceinline__ void fma4(float4& acc, float s, const float4& m) {
  acc.x += s * m.x;
  acc.y += s * m.y;
  acc.z += s * m.z;
  acc.w += s * m.w;
}

__global__ __launch_bounds__(256) void gemm128_kernel(
    const __half* __restrict__ X, const float* __restrict__ W,
    __half* __restrict__ Y, int nrows) {
  __shared__ float Wl[128 * 128];
  float4* Wl4 = (float4*)Wl;
  const float4* W4 = (const float4*)W;
  for (int i = threadIdx.x; i < 128 * 32; i += 256) Wl4[i] = W4[i];
  __syncthreads();

  int tc = threadIdx.x & 15;
  int tr = threadIdx.x >> 4;
  int base = blockIdx.x * 64;
  int r[4];
  bool v[4];
#pragma unroll
  for (int j = 0; j < 4; ++j) {
    int rr = base + tr + j * 16;
    v[j] = rr < nrows;
    r[j] = v[j] ? rr : 0;
  }
  float4 acc[4][2];
#pragma unroll
  for (int j = 0; j < 4; ++j) {
    acc[j][0] = make_float4(0.f, 0.f, 0.f, 0.f);
    acc[j][1] = make_float4(0.f, 0.f, 0.f, 0.f);
  }
#pragma unroll 4
  for (int k4 = 0; k4 < 32; ++k4) {
    float4 xv[4];
#pragma unroll
    for (int j = 0; j < 4; ++j)
      xv[j] = h4_to_f4(((const half4*)X)[(size_t)r[j] * 32 + k4]);
#pragma unroll
    for (int kk = 0; kk < 4; ++kk) {
      float4 wva = Wl4[(k4 * 4 + kk) * 32 + tc];
      float4 wvb = Wl4[(k4 * 4 + kk) * 32 + 16 + tc];
#pragma unroll
      for (int j = 0; j < 4; ++j) {
        float xk = ((const float*)&xv[j])[kk];
        fma4(acc[j][0], xk, wva);
        fma4(acc[j][1], xk, wvb);
      }
    }
  }
#pragma unroll
  for (int j = 0; j < 4; ++j) {
    if (v[j]) {
      ((half4*)Y)[(size_t)r[j] * 32 + tc] = f4_to_h4(acc[j][0]);
      ((half4*)Y)[(size_t)r[j] * 32 + 16 + tc] = f4_to_h4(acc[j][1]);
    }
  }
}

// ---------------- edge aggregation (unroll 8): eraw = Binv * sum h -------
__global__ __launch_bounds__(256) void edge_agg_kernel(
    const __half* __restrict__ hin, const int* __restrict__ eptr,
    const int* __restrict__ edge_nodes, const float* __restrict__ Binv,
    __half* __restrict__ eout) {
  int half_id = threadIdx.x >> 5;
  int lane = threadIdx.x & 31;
  int m = blockIdx.x * 8 + half_id;
  if (m >= MM) return;
  int lo = eptr[m], hi = eptr[m + 1];
  const half4* h4p = (const half4*)hin;
  float4 acc = make_float4(0.f, 0.f, 0.f, 0.f);
  int j = lo;
  for (; j + 8 <= hi; j += 8) {
    int idx[8];
#pragma unroll
    for (int u = 0; u < 8; ++u) idx[u] = edge_nodes[j + u];
    float4 s[8];
#pragma unroll
    for (int u = 0; u < 8; ++u) s[u] = h4_to_f4(h4p[(size_t)idx[u] * 32 + lane]);
    acc.x += ((s[0].x + s[1].x) + (s[2].x + s[3].x)) + ((s[4].x + s[5].x) + (s[6].x + s[7].x));
    acc.y += ((s[0].y + s[1].y) + (s[2].y + s[3].y)) + ((s[4].y + s[5].y) + (s[6].y + s[7].y));
    acc.z += ((s[0].z + s[1].z) + (s[2].z + s[3].z)) + ((s[4].z + s[5].z) + (s[6].z + s[7].z));
    acc.w += ((s[0].w + s[1].w) + (s[2].w + s[3].w)) + ((s[4].w + s[5].w) + (s[6].w + s[7].w));
  }
  for (; j < hi; ++j) {
    int n = edge_nodes[j];
    float4 a = h4_to_f4(h4p[(size_t)n * 32 + lane]);
    acc.x += a.x; acc.y += a.y; acc.z += a.z; acc.w += a.w;
  }
  float bi = Binv[m];
  acc.x *= bi; acc.y *= bi; acc.z *= bi; acc.w *= bi;
  ((half4*)eout)[(size_t)m * 32 + lane] = f4_to_h4(acc);
}

// ---------------- node aggregation, CHANNEL-HALF pass --------------------
// Each pass covers 64 channels (16 half4); source half-table (2.56 MB) is
// XCD-L2-resident. 16-lane group per node; 16 nodes per 256-thr block.
__device__ __forceinline__ void strow_q(float* Y, size_t row, int q, float4 v) {
  ((float4*)Y)[row * 32 + q] = v;
}
__device__ __forceinline__ void strow_q(__half* Y, size_t row, int q, float4 v) {
  ((half4*)Y)[row * 32 + q] = f4_to_h4(v);
}

template <typename TOUT>
__global__ __launch_bounds__(256) void node_agg_half_kernel(
    const __half* __restrict__ ein, const int* __restrict__ nptr,
    const int* __restrict__ node_edges, const float* __restrict__ Dinv,
    const float* __restrict__ bias, TOUT* __restrict__ out, int c4) {
  int g = threadIdx.x >> 4;     // 16 groups
  int gl = threadIdx.x & 15;    // lane in group
  int n = blockIdx.x * 16 + g;  // 6250 * 16 = 100000 exactly
  int q = c4 + gl;              // half4 index within the 32-half4 row
  int lo = nptr[n], hi = nptr[n + 1];
  const half4* e4 = (const half4*)ein;
  float4 acc = make_float4(0.f, 0.f, 0.f, 0.f);
  int j = lo;
  for (; j + 4 <= hi; j += 4) {
    int m0 = node_edges[j + 0];
    int m1 = node_edges[j + 1];
    int m2 = node_edges[j + 2];
    int m3 = node_edges[j + 3];
    float4 a = h4_to_f4(e4[(size_t)m0 * 32 + q]);
    float4 b = h4_to_f4(e4[(size_t)m1 * 32 + q]);
    float4 c = h4_to_f4(e4[(size_t)m2 * 32 + q]);
    float4 d = h4_to_f4(e4[(size_t)m3 * 32 + q]);
    acc.x += (a.x + b.x) + (c.x + d.x);
    acc.y += (a.y + b.y) + (c.y + d.y);
    acc.z += (a.z + b.z) + (c.z + d.z);
    acc.w += (a.w + b.w) + (c.w + d.w);
  }
  for (; j < hi; ++j) {
    int m = node_edges[j];
    float4 a = h4_to_f4(e4[(size_t)m * 32 + q]);
    acc.x += a.x; acc.y += a.y; acc.z += a.z; acc.w += a.w;
  }
  float di = Dinv[n];
  float4 bb = ((const float4*)bias)[q];
  float4 rv;
  rv.x = fmaxf(di * acc.x + bb.x, 0.f);
  rv.y = fmaxf(di * acc.y + bb.y, 0.f);
  rv.z = fmaxf(di * acc.z + bb.z, 0.f);
  rv.w = fmaxf(di * acc.w + bb.w, 0.f);
  strow_q(out, (size_t)n, q, rv);
}

// ---------------- host-side launch ---------------------------------------
extern "C" void kernel_launch(void* const* d_in, const int* in_sizes, int n_in,
                              void* d_out, int out_size, void* d_ws, size_t ws_size,
                              hipStream_t stream) {
  const float* x = (const float*)d_in[0];
  const int* hidx = (const int*)d_in[1];
  const int* node_idx = hidx;        // hyperedge_index[0]
  const int* edge_idx = hidx + EE;   // hyperedge_index[1]
  const float* hw = (const float*)d_in[2];
  // d_in[3] = hyperedge_attr (unused), d_in[4] = batch (unused)
  const float* W1 = (const float*)d_in[5];
  const float* b1 = (const float*)d_in[6];
  const float* W2 = (const float*)d_in[7];
  const float* b2 = (const float*)d_in[8];
  const float* W3 = (const float*)d_in[9];
  const float* b3 = (const float*)d_in[10];
  float* out = (float*)d_out;

  char* ws = (char*)d_ws;
  size_t off = 0;
  auto alloc = [&](size_t bytes) -> char* {
    char* p = ws + off;
    off = align256(off + bytes);
    return p;
  };
  __half* xh   = (__half*)alloc(sizeof(__half) * (size_t)NN * 128);  // 25.6 MB
  __half* h    = (__half*)alloc(sizeof(__half) * (size_t)NN * 128);  // 25.6 MB
  __half* eraw = (__half*)alloc(sizeof(__half) * (size_t)MM * 128);  // 5.12 MB
  __half* et   = (__half*)alloc(sizeof(__half) * (size_t)MM * 128);  // 5.12 MB
  unsigned short* bcnt_e = (unsigned short*)alloc(sizeof(short) * (size_t)NBLK_E * MM); // 10.2 MB
  unsigned short* bcnt_n = (unsigned short*)alloc(sizeof(short) * (size_t)NBLK_N * NN); // 25.6 MB
  unsigned short* lrank_e = (unsigned short*)alloc(sizeof(short) * (size_t)EE);
  unsigned short* lrank_n = (unsigned short*)alloc(sizeof(short) * (size_t)EE);
  int*   ecnt  = (int*)alloc(sizeof(int) * MM);
  int*   ncnt  = (int*)alloc(sizeof(int) * NN);
  int*   eptr  = (int*)alloc(sizeof(int) * (MM + 1));
  int*   nptr  = (int*)alloc(sizeof(int) * (NN + 1));
  int*   bsum  = (int*)alloc(sizeof(int) * NB_TOT);
  float* Binv  = (float*)alloc(sizeof(float) * MM);
  float* Dinv  = (float*)alloc(sizeof(float) * NN);
  int* edge_nodes = (int*)alloc(sizeof(int) * (size_t)EE);           // 6.4 MB
  int* node_edges = (int*)alloc(sizeof(int) * (size_t)EE);           // 6.4 MB
  (void)ws_size; (void)in_sizes; (void)n_in; (void)out_size;

  // ---- graph precompute: no global atomics anywhere --------------------
  ehist_kernel<<<NBLK_E, 256, MM * sizeof(int), stream>>>(edge_idx, bcnt_e, lrank_e);
  nhist_kernel<<<NBLK_N, 256, (NRANGE2 / 2) * sizeof(int), stream>>>(node_idx, bcnt_n, lrank_n);
  colscan_kernel<<<(MM + NN + 255) / 256, 256, 0, stream>>>(bcnt_e, bcnt_n, ecnt, ncnt);
  scan_partial_kernel<<<NB_TOT, SCAN_BLOCK, 0, stream>>>(ecnt, ncnt, eptr, nptr, bsum);
  scan_bsum_kernel<<<1, 64, 0, stream>>>(bsum);
  scan_fixup_kernel<<<NB_TOT, SCAN_BLOCK, 0, stream>>>(eptr, nptr, ecnt, bsum, Binv);
  fill2_kernel<<<(EE + 255) / 256, 256, 0, stream>>>(node_idx, edge_idx, eptr, nptr,
                                                     bcnt_e, bcnt_n, lrank_e, lrank_n,
                                                     edge_nodes, node_edges);
  dinv_csr_kernel<<<(NN + 255) / 256, 256, 0, stream>>>(nptr, node_edges, hw, Dinv);
  cvt_f2h_kernel<<<1024, 256, 0, stream>>>(x, xh, NN * 32);

  const int gemmE_grid = (MM + 63) / 64;
  const int eagg_grid = MM / 8;     // 20000 % 8 == 0
  const int nagg_grid = NN / 16;    // 100000 % 16 == 0

  // ---- layer 1: eagg(xh) -> gemm(W1) -> nagg x2 halves (+b1, relu) ----
  edge_agg_kernel<<<eagg_grid, 256, 0, stream>>>(xh, eptr, edge_nodes, Binv, eraw);
  gemm128_kernel<<<gemmE_grid, 256, 0, stream>>>(eraw, W1, et, MM);
  node_agg_half_kernel<__half><<<nagg_grid, 256, 0, stream>>>(et, nptr, node_edges, Dinv, b1, h, 0);
  node_agg_half_kernel<__half><<<nagg_grid, 256, 0, stream>>>(et, nptr, node_edges, Dinv, b1, h, 16);
  // ---- layer 2 (reuse xh as the second ping-pong buffer) ----
  edge_agg_kernel<<<eagg_grid, 256, 0, stream>>>(h, eptr, edge_nodes, Binv, eraw);
  gemm128_kernel<<<gemmE_grid, 256, 0, stream>>>(eraw, W2, et, MM);
  node_agg_half_kernel<__half><<<nagg_grid, 256, 0, stream>>>(et, nptr, node_edges, Dinv, b2, xh, 0);
  node_agg_half_kernel<__half><<<nagg_grid, 256, 0, stream>>>(et, nptr, node_edges, Dinv, b2, xh, 16);
  // ---- layer 3 ----
  edge_agg_kernel<<<eagg_grid, 256, 0, stream>>>(xh, eptr, edge_nodes, Binv, eraw);
  gemm128_kernel<<<gemmE_grid, 256, 0, stream>>>(eraw, W3, et, MM);
  node_agg_half_kernel<float><<<nagg_grid, 256, 0, stream>>>(et, nptr, node_edges, Dinv, b3, out, 0);
  node_agg_half_kernel<float><<<nagg_grid, 256, 0, stream>>>(et, nptr, node_edges, Dinv, b3, out, 16);
}